// Round 1
// baseline (462.880 us; speedup 1.0000x reference)
//
#include <hip/hip_runtime.h>

#define N_NODES 50000
#define NEDGE   400000

typedef __bf16 bf16x8 __attribute__((ext_vector_type(8)));
typedef float  f32x4  __attribute__((ext_vector_type(4)));

#define GLDS16(gp, lp) \
  __builtin_amdgcn_global_load_lds((const __attribute__((address_space(1))) void*)(gp), \
                                   (__attribute__((address_space(3))) void*)(lp), 16, 0, 0)

static __device__ __forceinline__ unsigned short f2bf(float f) {
  unsigned u = __float_as_uint(f);
  unsigned r = (u + 0x7fffu + ((u >> 16) & 1u)) >> 16;   // RNE
  return (unsigned short)r;
}
static __device__ __forceinline__ float bf2f(unsigned short v) {
  return __uint_as_float((unsigned)v << 16);
}

// ---------------- prep: Wt[r*256+n][k] = (Wr[r] @ theta_r)[k][n], bf16; biasvec ----------------
__global__ void prep_kernel(const float* __restrict__ basis, const float* __restrict__ att,
                            const float* __restrict__ theta1, const float* __restrict__ theta2,
                            const float* __restrict__ bias1, const float* __restrict__ bias2,
                            unsigned short* __restrict__ Wt, float* __restrict__ biasvec) {
  const int bid = blockIdx.x;            // 0..511 : r*256 + k
  const int r = bid >> 8, k = bid & 255;
  const int n = threadIdx.x;             // 0..255
  const float a0 = att[r * 2 + 0], a1 = att[r * 2 + 1];
  const float* th = (r == 0) ? theta1 : theta2;
  float acc = 0.f;
  for (int j = 0; j < 256; ++j) {
    const float wr = a0 * basis[k * 256 + j] + a1 * basis[65536 + k * 256 + j]; // uniform: scalar load
    acc += wr * th[j * 256 + n];                                                // coalesced
  }
  Wt[(size_t)(r * 256 + n) * 256 + k] = f2bf(acc);
  if (k == 0) biasvec[r * 256 + n] = (r == 0) ? bias1[n] : bias2[n];
}

// ---------------- cast node_reps f32 -> bf16 ----------------
__global__ void cast_kernel(const float* __restrict__ in, unsigned short* __restrict__ out) {
  const long total = (long)N_NODES * 256 / 4;
  long idx = (long)blockIdx.x * blockDim.x + threadIdx.x;
  const long stride = (long)gridDim.x * blockDim.x;
  for (; idx < total; idx += stride) {
    float4 v = ((const float4*)in)[idx];
    ushort4 o;
    o.x = f2bf(v.x); o.y = f2bf(v.y); o.z = f2bf(v.z); o.w = f2bf(v.w);
    ((ushort4*)out)[idx] = o;
  }
}

// ---------------- GEMM: H[M][512] = A[M][256] @ W[256][512] + biasvec, bf16 MFMA ----------------
__global__ __launch_bounds__(256) void gemm_kernel(
    const unsigned short* __restrict__ A,    // [M][256] bf16
    const unsigned short* __restrict__ Wt,   // [512][256] bf16 (N-major, i.e. B^T)
    const float* __restrict__ biasvec,       // [512]
    unsigned short* __restrict__ H) {        // [M][512] bf16
  __shared__ unsigned short sA[128 * 64];
  __shared__ unsigned short sB[128 * 64];
  const int tid = threadIdx.x;
  const int wave = tid >> 6, lane = tid & 63;
  const int wm = wave >> 1, wn = wave & 1;
  const int m0 = blockIdx.y * 128;
  const int n0 = blockIdx.x * 128;

  f32x4 acc[4][4];
#pragma unroll
  for (int a = 0; a < 4; ++a)
#pragma unroll
    for (int b = 0; b < 4; ++b) acc[a][b] = (f32x4){0.f, 0.f, 0.f, 0.f};

  // staging geometry: chunk = 8 rows x 64 k (1KB). lane -> (row srow, swizzled k)
  const int srow = lane >> 3;                      // 0..7
  const int skel = ((lane & 7) ^ srow) << 3;       // pre-swizzled source k element

  for (int ks = 0; ks < 4; ++ks) {
    const int kg = ks * 64 + skel;
#pragma unroll
    for (int c = 0; c < 4; ++c) {
      const int chunk = wave * 4 + c;              // 0..15
      const int row = chunk * 8 + srow;            // 0..127
      int rowg = m0 + row;
      rowg = rowg < N_NODES ? rowg : N_NODES - 1;  // clamp (writes are guarded)
      GLDS16(A + (size_t)rowg * 256 + kg, sA + chunk * 512);
      GLDS16(Wt + (size_t)(n0 + row) * 256 + kg, sB + chunk * 512);
    }
    __syncthreads();
#pragma unroll
    for (int kk = 0; kk < 2; ++kk) {
      const int kb = (kk * 32 + ((lane >> 4) << 3)) << 1;  // logical k byte offset in row
      bf16x8 af[4], bfr[4];
#pragma unroll
      for (int m16 = 0; m16 < 4; ++m16) {
        const int row = wm * 64 + m16 * 16 + (lane & 15);
        af[m16] = *(const bf16x8*)((const char*)sA + row * 128 + (kb ^ ((row & 7) << 4)));
      }
#pragma unroll
      for (int n16 = 0; n16 < 4; ++n16) {
        const int col = wn * 64 + n16 * 16 + (lane & 15);
        bfr[n16] = *(const bf16x8*)((const char*)sB + col * 128 + (kb ^ ((col & 7) << 4)));
      }
#pragma unroll
      for (int m16 = 0; m16 < 4; ++m16)
#pragma unroll
        for (int n16 = 0; n16 < 4; ++n16)
          acc[m16][n16] = __builtin_amdgcn_mfma_f32_16x16x32_bf16(af[m16], bfr[n16], acc[m16][n16], 0, 0, 0);
    }
    __syncthreads();
  }
  // epilogue: C/D layout col=lane&15, row=(lane>>4)*4+j  [m89-verified]
#pragma unroll
  for (int n16 = 0; n16 < 4; ++n16) {
    const int colg = n0 + wn * 64 + n16 * 16 + (lane & 15);
    const float bv = biasvec[colg];
#pragma unroll
    for (int m16 = 0; m16 < 4; ++m16) {
      const int rowb = m0 + wm * 64 + m16 * 16 + ((lane >> 4) << 2);
#pragma unroll
      for (int j = 0; j < 4; ++j) {
        const int rowg = rowb + j;
        if (rowg < N_NODES)
          H[(size_t)rowg * 512 + colg] = f2bf(acc[m16][n16][j] + bv);
      }
    }
  }
}

// ---------------- per-node dots: s/d = h . w_src / w_dst (pos & neg) ----------------
__global__ void dot_kernel(const unsigned short* __restrict__ H,
                           const float* __restrict__ mapping,
                           float* __restrict__ sp, float* __restrict__ dp,
                           float* __restrict__ sn, float* __restrict__ dn) {
  const int lane = threadIdx.x & 63;
  const int i = blockIdx.x * 4 + (threadIdx.x >> 6);
  const ushort4* p = (const ushort4*)(H + (size_t)i * 512 + lane * 8);
  const ushort4 v0 = p[0], v1 = p[1];
  const unsigned short vs[8] = {v0.x, v0.y, v0.z, v0.w, v1.x, v1.y, v1.z, v1.w};
  float ps = 0.f, pd = 0.f;
  const int cbase = lane * 8;
#pragma unroll
  for (int q = 0; q < 8; ++q) {
    const float h = bf2f(vs[q]);
    const int cm = (cbase + q) & 255;
    ps += h * mapping[cm];
    pd += h * mapping[256 + cm];
  }
#pragma unroll
  for (int off = 1; off <= 16; off <<= 1) {   // reduce within 32-lane halves
    ps += __shfl_xor(ps, off);
    pd += __shfl_xor(pd, off);
  }
  if (lane == 0)       { sp[i] = ps; dp[i] = pd; }
  else if (lane == 32) { sn[i] = ps; dn[i] = pd; }
}

// ---------------- edges: raw coeff (sigmoid(leaky)) + per-row counts ----------------
__global__ void edge_kernel(const int* __restrict__ adjp, const int* __restrict__ adjn,
                            const float* __restrict__ sp, const float* __restrict__ dp,
                            const float* __restrict__ sn, const float* __restrict__ dn,
                            float* __restrict__ c0p, float* __restrict__ c0n,
                            int* __restrict__ cntp, int* __restrict__ cntn) {
  const int g = blockIdx.x * blockDim.x + threadIdx.x;
  if (g >= 2 * NEDGE) return;
  if (g < NEDGE) {
    const int src = adjp[g], dst = adjp[NEDGE + g];
    const float e = sp[src] + dp[dst];
    const float l = e > 0.f ? e : 0.2f * e;
    c0p[g] = 1.f / (1.f + expf(-l));
    atomicAdd(&cntp[src], 1);
  } else {
    const int e2 = g - NEDGE;
    const int src = adjn[e2], dst = adjn[NEDGE + e2];
    const float e = sn[src] + dn[dst];
    const float l = e > 0.f ? e : 0.2f * e;
    c0n[e2] = 1.f / (1.f + expf(-l));
    atomicAdd(&cntn[src], 1);
  }
}

// ---------------- single-block scan: row_start (exclusive) + rdeg ----------------
__global__ void scan_kernel(const int* __restrict__ cntp, const int* __restrict__ cntn,
                            int* __restrict__ rsp, int* __restrict__ rsn,
                            float* __restrict__ rdeg) {
  __shared__ int smp[1024], smn[1024];
  const int t = threadIdx.x;
  const int chunk = (N_NODES + 1023) >> 10;
  const int lo = t * chunk;
  const int hi = (lo + chunk < N_NODES) ? lo + chunk : N_NODES;
  int ap = 0, an = 0;
  for (int i = lo; i < hi; ++i) { ap += cntp[i]; an += cntn[i]; }
  smp[t] = ap; smn[t] = an;
  __syncthreads();
  for (int off = 1; off < 1024; off <<= 1) {
    const int vp = (t >= off) ? smp[t - off] : 0;
    const int vn = (t >= off) ? smn[t - off] : 0;
    __syncthreads();
    smp[t] += vp; smn[t] += vn;
    __syncthreads();
  }
  int rp = (t == 0) ? 0 : smp[t - 1];
  int rn = (t == 0) ? 0 : smn[t - 1];
  for (int i = lo; i < hi; ++i) {
    rsp[i] = rp; rsn[i] = rn;
    const int cp = cntp[i], cn = cntn[i];
    rp += cp; rn += cn;
    rdeg[i] = 1.f / sqrtf((float)(cp + cn));
  }
  if (t == 1023) { rsp[N_NODES] = smp[1023]; rsn[N_NODES] = smn[1023]; }
}

// ---------------- scatter into CSR with finalized coeff ----------------
__global__ void scatter_kernel(const int* __restrict__ adjp, const int* __restrict__ adjn,
                               const float* __restrict__ c0p, const float* __restrict__ c0n,
                               const float* __restrict__ rdeg,
                               const int* __restrict__ rsp, const int* __restrict__ rsn,
                               int* __restrict__ curp, int* __restrict__ curn,
                               int* __restrict__ colp, float* __restrict__ cfp,
                               int* __restrict__ coln, float* __restrict__ cfn) {
  const int g = blockIdx.x * blockDim.x + threadIdx.x;
  if (g >= 2 * NEDGE) return;
  if (g < NEDGE) {
    const int src = adjp[g], dst = adjp[NEDGE + g];
    const float c = c0p[g] * rdeg[src] * rdeg[dst];
    const int p = rsp[src] + atomicAdd(&curp[src], 1);
    colp[p] = dst; cfp[p] = c;
  } else {
    const int e2 = g - NEDGE;
    const int src = adjn[e2], dst = adjn[NEDGE + e2];
    const float c = c0n[e2] * rdeg[src] * rdeg[dst];
    const int p = rsn[src] + atomicAdd(&curn[src], 1);
    coln[p] = dst; cfn[p] = c;
  }
}

// ---------------- aggregate: one wave per row ----------------
__global__ __launch_bounds__(64) void agg_kernel(
    const unsigned short* __restrict__ H,
    const int* __restrict__ rsp, const int* __restrict__ colp, const float* __restrict__ cfp,
    const int* __restrict__ rsn, const int* __restrict__ coln, const float* __restrict__ cfn,
    const float* __restrict__ bias, float* __restrict__ out) {
  const int i = blockIdx.x;
  const int l = threadIdx.x;  // 0..63, 4 channels each
  float4 ap = {0.f, 0.f, 0.f, 0.f}, an = {0.f, 0.f, 0.f, 0.f};
  const int pb = rsp[i], pe = rsp[i + 1];
  for (int e = pb; e < pe; ++e) {
    const int col = colp[e];
    const float c = cfp[e];
    const ushort4 hv = *(const ushort4*)(H + (size_t)col * 512 + l * 4);
    ap.x += c * bf2f(hv.x); ap.y += c * bf2f(hv.y);
    ap.z += c * bf2f(hv.z); ap.w += c * bf2f(hv.w);
  }
  const int nb = rsn[i], ne = rsn[i + 1];
  for (int e = nb; e < ne; ++e) {
    const int col = coln[e];
    const float c = cfn[e];
    const ushort4 hv = *(const ushort4*)(H + (size_t)col * 512 + 256 + l * 4);
    an.x += c * bf2f(hv.x); an.y += c * bf2f(hv.y);
    an.z += c * bf2f(hv.z); an.w += c * bf2f(hv.w);
  }
  const float4 bv = ((const float4*)bias)[l];
  float4 o;
  o.x = ap.x - an.x + bv.x; o.y = ap.y - an.y + bv.y;
  o.z = ap.z - an.z + bv.z; o.w = ap.w - an.w + bv.w;
  ((float4*)out)[(size_t)i * 64 + l] = o;
  ((float4*)(out + (size_t)N_NODES * 256))[(size_t)i * 64 + l] = ap;
  ((float4*)(out + (size_t)2 * N_NODES * 256))[(size_t)i * 64 + l] = an;
}

extern "C" void kernel_launch(void* const* d_in, const int* in_sizes, int n_in,
                              void* d_out, int out_size, void* d_ws, size_t ws_size,
                              hipStream_t stream) {
  const float* node    = (const float*)d_in[0];
  const int*   adjp    = (const int*)d_in[1];
  const int*   adjn    = (const int*)d_in[2];
  const float* basis   = (const float*)d_in[3];
  const float* att     = (const float*)d_in[4];
  const float* mapping = (const float*)d_in[5];
  const float* bias    = (const float*)d_in[6];
  const float* theta1  = (const float*)d_in[7];
  const float* b1      = (const float*)d_in[8];
  const float* theta2  = (const float*)d_in[9];
  const float* b2      = (const float*)d_in[10];
  float* out = (float*)d_out;

  size_t off = 0;
  char* wsb = (char*)d_ws;
  auto alloc = [&](size_t bytes) -> char* {
    char* p = wsb + off;
    off = (off + bytes + 255) & ~(size_t)255;
    return p;
  };
  unsigned short* A16 = (unsigned short*)alloc((size_t)N_NODES * 256 * 2);
  unsigned short* H   = (unsigned short*)alloc((size_t)N_NODES * 512 * 2);
  unsigned short* Wt  = (unsigned short*)alloc(512 * 256 * 2);
  float* biasvec = (float*)alloc(512 * 4);
  float* sp   = (float*)alloc(N_NODES * 4);
  float* dp   = (float*)alloc(N_NODES * 4);
  float* sn   = (float*)alloc(N_NODES * 4);
  float* dn   = (float*)alloc(N_NODES * 4);
  float* rdeg = (float*)alloc(N_NODES * 4);
  int* cntp = (int*)alloc(N_NODES * 4);
  int* cntn = (int*)alloc(N_NODES * 4);
  int* curp = (int*)alloc(N_NODES * 4);
  int* curn = (int*)alloc(N_NODES * 4);
  int* rsp = (int*)alloc((N_NODES + 1) * 4);
  int* rsn = (int*)alloc((N_NODES + 1) * 4);
  float* c0p = (float*)alloc((size_t)NEDGE * 4);
  float* c0n = (float*)alloc((size_t)NEDGE * 4);
  int*   colp = (int*)alloc((size_t)NEDGE * 4);
  float* cfp  = (float*)alloc((size_t)NEDGE * 4);
  int*   coln = (int*)alloc((size_t)NEDGE * 4);
  float* cfn  = (float*)alloc((size_t)NEDGE * 4);

  hipMemsetAsync(cntp, 0, N_NODES * 4, stream);
  hipMemsetAsync(cntn, 0, N_NODES * 4, stream);
  hipMemsetAsync(curp, 0, N_NODES * 4, stream);
  hipMemsetAsync(curn, 0, N_NODES * 4, stream);

  prep_kernel<<<512, 256, 0, stream>>>(basis, att, theta1, theta2, b1, b2, Wt, biasvec);
  cast_kernel<<<2048, 256, 0, stream>>>(node, A16);
  gemm_kernel<<<dim3(4, 391), 256, 0, stream>>>(A16, Wt, biasvec, H);
  dot_kernel<<<N_NODES / 4, 256, 0, stream>>>(H, mapping, sp, dp, sn, dn);
  edge_kernel<<<(2 * NEDGE) / 256, 256, 0, stream>>>(adjp, adjn, sp, dp, sn, dn, c0p, c0n, cntp, cntn);
  scan_kernel<<<1, 1024, 0, stream>>>(cntp, cntn, rsp, rsn, rdeg);
  scatter_kernel<<<(2 * NEDGE) / 256, 256, 0, stream>>>(adjp, adjn, c0p, c0n, rdeg, rsp, rsn,
                                                        curp, curn, colp, cfp, coln, cfn);
  agg_kernel<<<N_NODES, 64, 0, stream>>>(H, rsp, colp, cfp, rsn, coln, cfn, bias, out);
}

// Round 2
// 298.475 us; speedup vs baseline: 1.5508x; 1.5508x over previous
//
#include <hip/hip_runtime.h>

#define N_NODES 50000
#define NEDGE   400000
#define SB      512
#define NSB     ((N_NODES + SB - 1) / SB)   // 98 scan blocks

typedef __bf16 bf16x8 __attribute__((ext_vector_type(8)));
typedef float  f32x4  __attribute__((ext_vector_type(4)));

#define GLDS16(gp, lp) \
  __builtin_amdgcn_global_load_lds((const __attribute__((address_space(1))) void*)(gp), \
                                   (__attribute__((address_space(3))) void*)(lp), 16, 0, 0)

static __device__ __forceinline__ unsigned short f2bf(float f) {
  unsigned u = __float_as_uint(f);
  unsigned r = (u + 0x7fffu + ((u >> 16) & 1u)) >> 16;   // RNE
  return (unsigned short)r;
}
static __device__ __forceinline__ float bf2f(unsigned short v) {
  return __uint_as_float((unsigned)v << 16);
}

// ---------------- prep: Wt[r*256+n][k] = (Wr[r] @ theta_r)[k][n], bf16; biasvec ----------------
__global__ void prep_kernel(const float* __restrict__ basis, const float* __restrict__ att,
                            const float* __restrict__ theta1, const float* __restrict__ theta2,
                            const float* __restrict__ bias1, const float* __restrict__ bias2,
                            unsigned short* __restrict__ Wt, float* __restrict__ biasvec) {
  const int bid = blockIdx.x;            // 0..511 : r*256 + k
  const int r = bid >> 8, k = bid & 255;
  const int n = threadIdx.x;             // 0..255
  const float a0 = att[r * 2 + 0], a1 = att[r * 2 + 1];
  const float* th = (r == 0) ? theta1 : theta2;
  float acc = 0.f;
  for (int j = 0; j < 256; ++j) {
    const float wr = a0 * basis[k * 256 + j] + a1 * basis[65536 + k * 256 + j]; // uniform: scalar load
    acc += wr * th[j * 256 + n];                                                // coalesced
  }
  Wt[(size_t)(r * 256 + n) * 256 + k] = f2bf(acc);
  if (k == 0) biasvec[r * 256 + n] = (r == 0) ? bias1[n] : bias2[n];
}

// ---------------- cast node_reps f32 -> bf16 ----------------
__global__ void cast_kernel(const float* __restrict__ in, unsigned short* __restrict__ out) {
  const long total = (long)N_NODES * 256 / 4;
  long idx = (long)blockIdx.x * blockDim.x + threadIdx.x;
  const long stride = (long)gridDim.x * blockDim.x;
  for (; idx < total; idx += stride) {
    float4 v = ((const float4*)in)[idx];
    ushort4 o;
    o.x = f2bf(v.x); o.y = f2bf(v.y); o.z = f2bf(v.z); o.w = f2bf(v.w);
    ((ushort4*)out)[idx] = o;
  }
}

// ---------------- GEMM: H[M][512] = A[M][256] @ W[256][512] + biasvec, bf16 MFMA ----------------
__global__ __launch_bounds__(256) void gemm_kernel(
    const unsigned short* __restrict__ A,    // [M][256] bf16
    const unsigned short* __restrict__ Wt,   // [512][256] bf16 (N-major, i.e. B^T)
    const float* __restrict__ biasvec,       // [512]
    unsigned short* __restrict__ H) {        // [M][512] bf16
  __shared__ unsigned short sA[128 * 64];
  __shared__ unsigned short sB[128 * 64];
  const int tid = threadIdx.x;
  const int wave = tid >> 6, lane = tid & 63;
  const int wm = wave >> 1, wn = wave & 1;
  const int m0 = blockIdx.y * 128;
  const int n0 = blockIdx.x * 128;

  f32x4 acc[4][4];
#pragma unroll
  for (int a = 0; a < 4; ++a)
#pragma unroll
    for (int b = 0; b < 4; ++b) acc[a][b] = (f32x4){0.f, 0.f, 0.f, 0.f};

  // staging geometry: chunk = 8 rows x 64 k (1KB). lane -> (row srow, swizzled k)
  const int srow = lane >> 3;                      // 0..7
  const int skel = ((lane & 7) ^ srow) << 3;       // pre-swizzled source k element

  for (int ks = 0; ks < 4; ++ks) {
    const int kg = ks * 64 + skel;
#pragma unroll
    for (int c = 0; c < 4; ++c) {
      const int chunk = wave * 4 + c;              // 0..15
      const int row = chunk * 8 + srow;            // 0..127
      int rowg = m0 + row;
      rowg = rowg < N_NODES ? rowg : N_NODES - 1;  // clamp (writes are guarded)
      GLDS16(A + (size_t)rowg * 256 + kg, sA + chunk * 512);
      GLDS16(Wt + (size_t)(n0 + row) * 256 + kg, sB + chunk * 512);
    }
    __syncthreads();
#pragma unroll
    for (int kk = 0; kk < 2; ++kk) {
      const int kb = (kk * 32 + ((lane >> 4) << 3)) << 1;  // logical k byte offset in row
      bf16x8 af[4], bfr[4];
#pragma unroll
      for (int m16 = 0; m16 < 4; ++m16) {
        const int row = wm * 64 + m16 * 16 + (lane & 15);
        af[m16] = *(const bf16x8*)((const char*)sA + row * 128 + (kb ^ ((row & 7) << 4)));
      }
#pragma unroll
      for (int n16 = 0; n16 < 4; ++n16) {
        const int col = wn * 64 + n16 * 16 + (lane & 15);
        bfr[n16] = *(const bf16x8*)((const char*)sB + col * 128 + (kb ^ ((col & 7) << 4)));
      }
#pragma unroll
      for (int m16 = 0; m16 < 4; ++m16)
#pragma unroll
        for (int n16 = 0; n16 < 4; ++n16)
          acc[m16][n16] = __builtin_amdgcn_mfma_f32_16x16x32_bf16(af[m16], bfr[n16], acc[m16][n16], 0, 0, 0);
    }
    __syncthreads();
  }
  // epilogue: C/D layout col=lane&15, row=(lane>>4)*4+j  [m89-verified]
#pragma unroll
  for (int n16 = 0; n16 < 4; ++n16) {
    const int colg = n0 + wn * 64 + n16 * 16 + (lane & 15);
    const float bv = biasvec[colg];
#pragma unroll
    for (int m16 = 0; m16 < 4; ++m16) {
      const int rowb = m0 + wm * 64 + m16 * 16 + ((lane >> 4) << 2);
#pragma unroll
      for (int j = 0; j < 4; ++j) {
        const int rowg = rowb + j;
        if (rowg < N_NODES)
          H[(size_t)rowg * 512 + colg] = f2bf(acc[m16][n16][j] + bv);
      }
    }
  }
}

// ---------------- per-node dots: s/d = h . w_src / w_dst (pos & neg) ----------------
__global__ void dot_kernel(const unsigned short* __restrict__ H,
                           const float* __restrict__ mapping,
                           float* __restrict__ sp, float* __restrict__ dp,
                           float* __restrict__ sn, float* __restrict__ dn) {
  const int lane = threadIdx.x & 63;
  const int i = blockIdx.x * 4 + (threadIdx.x >> 6);
  const ushort4* p = (const ushort4*)(H + (size_t)i * 512 + lane * 8);
  const ushort4 v0 = p[0], v1 = p[1];
  const unsigned short vs[8] = {v0.x, v0.y, v0.z, v0.w, v1.x, v1.y, v1.z, v1.w};
  float ps = 0.f, pd = 0.f;
  const int cbase = lane * 8;
#pragma unroll
  for (int q = 0; q < 8; ++q) {
    const float h = bf2f(vs[q]);
    const int cm = (cbase + q) & 255;
    ps += h * mapping[cm];
    pd += h * mapping[256 + cm];
  }
#pragma unroll
  for (int off = 1; off <= 16; off <<= 1) {   // reduce within 32-lane halves
    ps += __shfl_xor(ps, off);
    pd += __shfl_xor(pd, off);
  }
  if (lane == 0)       { sp[i] = ps; dp[i] = pd; }
  else if (lane == 32) { sn[i] = ps; dn[i] = pd; }
}

// ---------------- edges: raw coeff (sigmoid(leaky)) + per-row counts ----------------
__global__ void edge_kernel(const int* __restrict__ adjp, const int* __restrict__ adjn,
                            const float* __restrict__ sp, const float* __restrict__ dp,
                            const float* __restrict__ sn, const float* __restrict__ dn,
                            float* __restrict__ c0p, float* __restrict__ c0n,
                            int* __restrict__ cntp, int* __restrict__ cntn) {
  const int g = blockIdx.x * blockDim.x + threadIdx.x;
  if (g >= 2 * NEDGE) return;
  if (g < NEDGE) {
    const int src = adjp[g], dst = adjp[NEDGE + g];
    const float e = sp[src] + dp[dst];
    const float l = e > 0.f ? e : 0.2f * e;
    c0p[g] = 1.f / (1.f + expf(-l));
    atomicAdd(&cntp[src], 1);
  } else {
    const int e2 = g - NEDGE;
    const int src = adjn[e2], dst = adjn[NEDGE + e2];
    const float e = sn[src] + dn[dst];
    const float l = e > 0.f ? e : 0.2f * e;
    c0n[e2] = 1.f / (1.f + expf(-l));
    atomicAdd(&cntn[src], 1);
  }
}

// ---------------- scan phase 1: per-block partial sums ----------------
__global__ __launch_bounds__(SB) void scan1_kernel(const int* __restrict__ cntp,
                                                   const int* __restrict__ cntn,
                                                   int* __restrict__ bsp, int* __restrict__ bsn) {
  __shared__ int lp[SB / 64], ln[SB / 64];
  const int i = blockIdx.x * SB + threadIdx.x;
  int vp = (i < N_NODES) ? cntp[i] : 0;
  int vn = (i < N_NODES) ? cntn[i] : 0;
#pragma unroll
  for (int off = 1; off < 64; off <<= 1) { vp += __shfl_xor(vp, off); vn += __shfl_xor(vn, off); }
  const int wave = threadIdx.x >> 6, lane = threadIdx.x & 63;
  if (lane == 0) { lp[wave] = vp; ln[wave] = vn; }
  __syncthreads();
  if (threadIdx.x == 0) {
    int ap = 0, an = 0;
#pragma unroll
    for (int w = 0; w < SB / 64; ++w) { ap += lp[w]; an += ln[w]; }
    bsp[blockIdx.x] = ap; bsn[blockIdx.x] = an;
  }
}

// ---------------- scan phase 2: scan the 98 block sums (one small block) ----------------
__global__ void scan2_kernel(int* __restrict__ bsp, int* __restrict__ bsn,
                             int* __restrict__ rsp, int* __restrict__ rsn) {
  __shared__ int sp_[128], sn_[128];
  const int t = threadIdx.x;
  sp_[t] = (t < NSB) ? bsp[t] : 0;
  sn_[t] = (t < NSB) ? bsn[t] : 0;
  __syncthreads();
  for (int off = 1; off < 128; off <<= 1) {
    const int ap = (t >= off) ? sp_[t - off] : 0;
    const int an = (t >= off) ? sn_[t - off] : 0;
    __syncthreads();
    sp_[t] += ap; sn_[t] += an;
    __syncthreads();
  }
  if (t < NSB) { bsp[t] = (t == 0) ? 0 : sp_[t - 1]; bsn[t] = (t == 0) ? 0 : sn_[t - 1]; }
  if (t == 127) { rsp[N_NODES] = sp_[127]; rsn[N_NODES] = sn_[127]; }
}

// ---------------- scan phase 3: block scan + offset -> row starts + rdeg ----------------
__global__ __launch_bounds__(SB) void scan3_kernel(const int* __restrict__ cntp,
                                                   const int* __restrict__ cntn,
                                                   const int* __restrict__ bsp,
                                                   const int* __restrict__ bsn,
                                                   int* __restrict__ rsp, int* __restrict__ rsn,
                                                   float* __restrict__ rdeg) {
  __shared__ int sp_[SB], sn_[SB];
  const int t = threadIdx.x;
  const int i = blockIdx.x * SB + t;
  const int cp = (i < N_NODES) ? cntp[i] : 0;
  const int cn = (i < N_NODES) ? cntn[i] : 0;
  sp_[t] = cp; sn_[t] = cn;
  __syncthreads();
  for (int off = 1; off < SB; off <<= 1) {
    const int ap = (t >= off) ? sp_[t - off] : 0;
    const int an = (t >= off) ? sn_[t - off] : 0;
    __syncthreads();
    sp_[t] += ap; sn_[t] += an;
    __syncthreads();
  }
  if (i < N_NODES) {
    rsp[i] = bsp[blockIdx.x] + sp_[t] - cp;   // exclusive
    rsn[i] = bsn[blockIdx.x] + sn_[t] - cn;
    rdeg[i] = 1.f / sqrtf((float)(cp + cn));
  }
}

// ---------------- scatter into CSR with finalized coeff ----------------
__global__ void scatter_kernel(const int* __restrict__ adjp, const int* __restrict__ adjn,
                               const float* __restrict__ c0p, const float* __restrict__ c0n,
                               const float* __restrict__ rdeg,
                               const int* __restrict__ rsp, const int* __restrict__ rsn,
                               int* __restrict__ curp, int* __restrict__ curn,
                               int* __restrict__ colp, float* __restrict__ cfp,
                               int* __restrict__ coln, float* __restrict__ cfn) {
  const int g = blockIdx.x * blockDim.x + threadIdx.x;
  if (g >= 2 * NEDGE) return;
  if (g < NEDGE) {
    const int src = adjp[g], dst = adjp[NEDGE + g];
    const float c = c0p[g] * rdeg[src] * rdeg[dst];
    const int p = rsp[src] + atomicAdd(&curp[src], 1);
    colp[p] = dst; cfp[p] = c;
  } else {
    const int e2 = g - NEDGE;
    const int src = adjn[e2], dst = adjn[NEDGE + e2];
    const float c = c0n[e2] * rdeg[src] * rdeg[dst];
    const int p = rsn[src] + atomicAdd(&curn[src], 1);
    coln[p] = dst; cfn[p] = c;
  }
}

// ---------------- aggregate: one wave per row, 4 rows per block ----------------
__global__ __launch_bounds__(256) void agg_kernel(
    const unsigned short* __restrict__ H,
    const int* __restrict__ rsp, const int* __restrict__ colp, const float* __restrict__ cfp,
    const int* __restrict__ rsn, const int* __restrict__ coln, const float* __restrict__ cfn,
    const float* __restrict__ bias, float* __restrict__ out) {
  const int i = blockIdx.x * 4 + (threadIdx.x >> 6);
  const int l = threadIdx.x & 63;  // 4 channels each
  float4 ap = {0.f, 0.f, 0.f, 0.f}, an = {0.f, 0.f, 0.f, 0.f};
  const int pb = rsp[i], pe = rsp[i + 1];
  for (int e = pb; e < pe; ++e) {
    const int col = colp[e];
    const float c = cfp[e];
    const ushort4 hv = *(const ushort4*)(H + (size_t)col * 512 + l * 4);
    ap.x += c * bf2f(hv.x); ap.y += c * bf2f(hv.y);
    ap.z += c * bf2f(hv.z); ap.w += c * bf2f(hv.w);
  }
  const int nb = rsn[i], ne = rsn[i + 1];
  for (int e = nb; e < ne; ++e) {
    const int col = coln[e];
    const float c = cfn[e];
    const ushort4 hv = *(const ushort4*)(H + (size_t)col * 512 + 256 + l * 4);
    an.x += c * bf2f(hv.x); an.y += c * bf2f(hv.y);
    an.z += c * bf2f(hv.z); an.w += c * bf2f(hv.w);
  }
  const float4 bv = ((const float4*)bias)[l];
  float4 o;
  o.x = ap.x - an.x + bv.x; o.y = ap.y - an.y + bv.y;
  o.z = ap.z - an.z + bv.z; o.w = ap.w - an.w + bv.w;
  ((float4*)out)[(size_t)i * 64 + l] = o;
  ((float4*)(out + (size_t)N_NODES * 256))[(size_t)i * 64 + l] = ap;
  ((float4*)(out + (size_t)2 * N_NODES * 256))[(size_t)i * 64 + l] = an;
}

extern "C" void kernel_launch(void* const* d_in, const int* in_sizes, int n_in,
                              void* d_out, int out_size, void* d_ws, size_t ws_size,
                              hipStream_t stream) {
  const float* node    = (const float*)d_in[0];
  const int*   adjp    = (const int*)d_in[1];
  const int*   adjn    = (const int*)d_in[2];
  const float* basis   = (const float*)d_in[3];
  const float* att     = (const float*)d_in[4];
  const float* mapping = (const float*)d_in[5];
  const float* bias    = (const float*)d_in[6];
  const float* theta1  = (const float*)d_in[7];
  const float* b1      = (const float*)d_in[8];
  const float* theta2  = (const float*)d_in[9];
  const float* b2      = (const float*)d_in[10];
  float* out = (float*)d_out;

  size_t off = 0;
  char* wsb = (char*)d_ws;
  auto alloc = [&](size_t bytes) -> char* {
    char* p = wsb + off;
    off = (off + bytes + 255) & ~(size_t)255;
    return p;
  };
  unsigned short* A16 = (unsigned short*)alloc((size_t)N_NODES * 256 * 2);
  unsigned short* H   = (unsigned short*)alloc((size_t)N_NODES * 512 * 2);
  unsigned short* Wt  = (unsigned short*)alloc(512 * 256 * 2);
  float* biasvec = (float*)alloc(512 * 4);
  float* sp   = (float*)alloc(N_NODES * 4);
  float* dp   = (float*)alloc(N_NODES * 4);
  float* sn   = (float*)alloc(N_NODES * 4);
  float* dn   = (float*)alloc(N_NODES * 4);
  float* rdeg = (float*)alloc(N_NODES * 4);
  int* cntp = (int*)alloc(N_NODES * 4);
  int* cntn = (int*)alloc(N_NODES * 4);
  int* curp = (int*)alloc(N_NODES * 4);
  int* curn = (int*)alloc(N_NODES * 4);
  int* rsp = (int*)alloc((N_NODES + 1) * 4);
  int* rsn = (int*)alloc((N_NODES + 1) * 4);
  int* bsp = (int*)alloc(NSB * 4);
  int* bsn = (int*)alloc(NSB * 4);
  float* c0p = (float*)alloc((size_t)NEDGE * 4);
  float* c0n = (float*)alloc((size_t)NEDGE * 4);
  int*   colp = (int*)alloc((size_t)NEDGE * 4);
  float* cfp  = (float*)alloc((size_t)NEDGE * 4);
  int*   coln = (int*)alloc((size_t)NEDGE * 4);
  float* cfn  = (float*)alloc((size_t)NEDGE * 4);

  hipMemsetAsync(cntp, 0, N_NODES * 4, stream);
  hipMemsetAsync(cntn, 0, N_NODES * 4, stream);
  hipMemsetAsync(curp, 0, N_NODES * 4, stream);
  hipMemsetAsync(curn, 0, N_NODES * 4, stream);

  prep_kernel<<<512, 256, 0, stream>>>(basis, att, theta1, theta2, b1, b2, Wt, biasvec);
  cast_kernel<<<2048, 256, 0, stream>>>(node, A16);
  gemm_kernel<<<dim3(4, 391), 256, 0, stream>>>(A16, Wt, biasvec, H);
  dot_kernel<<<N_NODES / 4, 256, 0, stream>>>(H, mapping, sp, dp, sn, dn);
  edge_kernel<<<(2 * NEDGE) / 256, 256, 0, stream>>>(adjp, adjn, sp, dp, sn, dn, c0p, c0n, cntp, cntn);
  scan1_kernel<<<NSB, SB, 0, stream>>>(cntp, cntn, bsp, bsn);
  scan2_kernel<<<1, 128, 0, stream>>>(bsp, bsn, rsp, rsn);
  scan3_kernel<<<NSB, SB, 0, stream>>>(cntp, cntn, bsp, bsn, rsp, rsn, rdeg);
  scatter_kernel<<<(2 * NEDGE) / 256, 256, 0, stream>>>(adjp, adjn, c0p, c0n, rdeg, rsp, rsn,
                                                        curp, curn, colp, cfp, coln, cfn);
  agg_kernel<<<N_NODES / 4, 256, 0, stream>>>(H, rsp, colp, cfp, rsn, coln, cfn, bias, out);
}

// Round 3
// 266.206 us; speedup vs baseline: 1.7388x; 1.1212x over previous
//
#include <hip/hip_runtime.h>

#define N_NODES 50000
#define NEDGE   400000
#define SB      512
#define NSB     ((N_NODES + SB - 1) / SB)   // 98 scan blocks

typedef __bf16 bf16x8 __attribute__((ext_vector_type(8)));
typedef float  f32x4  __attribute__((ext_vector_type(4)));

#define GLDS16(gp, lp) \
  __builtin_amdgcn_global_load_lds((const __attribute__((address_space(1))) void*)(gp), \
                                   (__attribute__((address_space(3))) void*)(lp), 16, 0, 0)

static __device__ __forceinline__ unsigned short f2bf(float f) {
  unsigned u = __float_as_uint(f);
  unsigned r = (u + 0x7fffu + ((u >> 16) & 1u)) >> 16;   // RNE
  return (unsigned short)r;
}
static __device__ __forceinline__ float bf2f(unsigned short v) {
  return __uint_as_float((unsigned)v << 16);
}

// ---------------- prep: Wt[r*256+n][k] = (Wr[r] @ theta_r)[k][n], bf16; biasvec ----------------
__global__ void prep_kernel(const float* __restrict__ basis, const float* __restrict__ att,
                            const float* __restrict__ theta1, const float* __restrict__ theta2,
                            const float* __restrict__ bias1, const float* __restrict__ bias2,
                            unsigned short* __restrict__ Wt, float* __restrict__ biasvec) {
  const int bid = blockIdx.x;            // 0..511 : r*256 + k
  const int r = bid >> 8, k = bid & 255;
  const int n = threadIdx.x;             // 0..255
  const float a0 = att[r * 2 + 0], a1 = att[r * 2 + 1];
  const float* th = (r == 0) ? theta1 : theta2;
  float acc = 0.f;
  for (int j = 0; j < 256; ++j) {
    const float wr = a0 * basis[k * 256 + j] + a1 * basis[65536 + k * 256 + j]; // uniform: scalar load
    acc += wr * th[j * 256 + n];                                                // coalesced
  }
  Wt[(size_t)(r * 256 + n) * 256 + k] = f2bf(acc);
  if (k == 0) biasvec[r * 256 + n] = (r == 0) ? bias1[n] : bias2[n];
}

// ---------------- cast node_reps f32 -> bf16 ----------------
__global__ void cast_kernel(const float* __restrict__ in, unsigned short* __restrict__ out) {
  const long total = (long)N_NODES * 256 / 4;
  long idx = (long)blockIdx.x * blockDim.x + threadIdx.x;
  const long stride = (long)gridDim.x * blockDim.x;
  for (; idx < total; idx += stride) {
    float4 v = ((const float4*)in)[idx];
    ushort4 o;
    o.x = f2bf(v.x); o.y = f2bf(v.y); o.z = f2bf(v.z); o.w = f2bf(v.w);
    ((ushort4*)out)[idx] = o;
  }
}

// ---- GEMM: H[M][512] = A[M][256] @ W[256][512] + biasvec, bf16 MFMA; fused per-node dots ----
__global__ __launch_bounds__(256) void gemm_kernel(
    const unsigned short* __restrict__ A,    // [M][256] bf16
    const unsigned short* __restrict__ Wt,   // [512][256] bf16 (N-major, i.e. B^T)
    const float* __restrict__ biasvec,       // [512]
    const float* __restrict__ mapping,       // [512]: w_src | w_dst
    unsigned short* __restrict__ H,          // [M][512] bf16
    float* __restrict__ spA, float* __restrict__ dpA,
    float* __restrict__ snA, float* __restrict__ dnA) {
  __shared__ unsigned short sA[128 * 64];
  __shared__ unsigned short sB[128 * 64];
  const int tid = threadIdx.x;
  const int wave = tid >> 6, lane = tid & 63;
  const int wm = wave >> 1, wn = wave & 1;
  const int m0 = blockIdx.y * 128;
  const int n0 = blockIdx.x * 128;

  f32x4 acc[4][4];
#pragma unroll
  for (int a = 0; a < 4; ++a)
#pragma unroll
    for (int b = 0; b < 4; ++b) acc[a][b] = (f32x4){0.f, 0.f, 0.f, 0.f};

  // staging geometry: chunk = 8 rows x 64 k (1KB). lane -> (row srow, swizzled k)
  const int srow = lane >> 3;                      // 0..7
  const int skel = ((lane & 7) ^ srow) << 3;       // pre-swizzled source k element

  for (int ks = 0; ks < 4; ++ks) {
    const int kg = ks * 64 + skel;
#pragma unroll
    for (int c = 0; c < 4; ++c) {
      const int chunk = wave * 4 + c;              // 0..15
      const int row = chunk * 8 + srow;            // 0..127
      int rowg = m0 + row;
      rowg = rowg < N_NODES ? rowg : N_NODES - 1;  // clamp (writes are guarded)
      GLDS16(A + (size_t)rowg * 256 + kg, sA + chunk * 512);
      GLDS16(Wt + (size_t)(n0 + row) * 256 + kg, sB + chunk * 512);
    }
    __syncthreads();
#pragma unroll
    for (int kk = 0; kk < 2; ++kk) {
      const int kb = (kk * 32 + ((lane >> 4) << 3)) << 1;  // logical k byte offset in row
      bf16x8 af[4], bfr[4];
#pragma unroll
      for (int m16 = 0; m16 < 4; ++m16) {
        const int row = wm * 64 + m16 * 16 + (lane & 15);
        af[m16] = *(const bf16x8*)((const char*)sA + row * 128 + (kb ^ ((row & 7) << 4)));
      }
#pragma unroll
      for (int n16 = 0; n16 < 4; ++n16) {
        const int col = wn * 64 + n16 * 16 + (lane & 15);
        bfr[n16] = *(const bf16x8*)((const char*)sB + col * 128 + (kb ^ ((col & 7) << 4)));
      }
#pragma unroll
      for (int m16 = 0; m16 < 4; ++m16)
#pragma unroll
        for (int n16 = 0; n16 < 4; ++n16)
          acc[m16][n16] = __builtin_amdgcn_mfma_f32_16x16x32_bf16(af[m16], bfr[n16], acc[m16][n16], 0, 0, 0);
    }
    __syncthreads();
  }
  // epilogue: C/D layout col=lane&15, row=(lane>>4)*4+j  [m89-verified]
  // fused: partial dots h.w_src / h.w_dst accumulated into sp/dp (pos cols) or sn/dn (neg cols)
  const bool sgn = (n0 >= 256);
  float* sArr = sgn ? snA : spA;
  float* dArr = sgn ? dnA : dpA;
  float bv[4], wsv[4], wdv[4];
#pragma unroll
  for (int n16 = 0; n16 < 4; ++n16) {
    const int colg = n0 + wn * 64 + n16 * 16 + (lane & 15);
    bv[n16] = biasvec[colg];
    const int cm = colg & 255;
    wsv[n16] = mapping[cm];
    wdv[n16] = mapping[256 + cm];
  }
#pragma unroll
  for (int m16 = 0; m16 < 4; ++m16) {
    const int rowb = m0 + wm * 64 + m16 * 16 + ((lane >> 4) << 2);
#pragma unroll
    for (int j = 0; j < 4; ++j) {
      const int rowg = rowb + j;      // uniform within each 16-lane subgroup
      float vs = 0.f, vd = 0.f;
#pragma unroll
      for (int n16 = 0; n16 < 4; ++n16) {
        const float v = acc[m16][n16][j] + bv[n16];
        const int colg = n0 + wn * 64 + n16 * 16 + (lane & 15);
        if (rowg < N_NODES) H[(size_t)rowg * 512 + colg] = f2bf(v);
        vs += v * wsv[n16];
        vd += v * wdv[n16];
      }
#pragma unroll
      for (int off = 1; off < 16; off <<= 1) { vs += __shfl_xor(vs, off); vd += __shfl_xor(vd, off); }
      if ((lane & 15) == 0 && rowg < N_NODES) {
        atomicAdd(&sArr[rowg], vs);
        atomicAdd(&dArr[rowg], vd);
      }
    }
  }
}

// ---------------- edges: per-row counts only ----------------
__global__ void count_kernel(const int* __restrict__ adjp, const int* __restrict__ adjn,
                             int* __restrict__ cntp, int* __restrict__ cntn) {
  const int g = blockIdx.x * blockDim.x + threadIdx.x;
  if (g >= 2 * NEDGE) return;
  if (g < NEDGE) atomicAdd(&cntp[adjp[g]], 1);
  else           atomicAdd(&cntn[adjn[g - NEDGE]], 1);
}

// ---------------- scan phase 1: per-block partial sums ----------------
__global__ __launch_bounds__(SB) void scan1_kernel(const int* __restrict__ cntp,
                                                   const int* __restrict__ cntn,
                                                   int* __restrict__ bsp, int* __restrict__ bsn) {
  __shared__ int lp[SB / 64], ln[SB / 64];
  const int i = blockIdx.x * SB + threadIdx.x;
  int vp = (i < N_NODES) ? cntp[i] : 0;
  int vn = (i < N_NODES) ? cntn[i] : 0;
#pragma unroll
  for (int off = 1; off < 64; off <<= 1) { vp += __shfl_xor(vp, off); vn += __shfl_xor(vn, off); }
  const int wave = threadIdx.x >> 6, lane = threadIdx.x & 63;
  if (lane == 0) { lp[wave] = vp; ln[wave] = vn; }
  __syncthreads();
  if (threadIdx.x == 0) {
    int ap = 0, an = 0;
#pragma unroll
    for (int w = 0; w < SB / 64; ++w) { ap += lp[w]; an += ln[w]; }
    bsp[blockIdx.x] = ap; bsn[blockIdx.x] = an;
  }
}

// ---------------- scan phase 2: scan the 98 block sums (one small block) ----------------
__global__ void scan2_kernel(int* __restrict__ bsp, int* __restrict__ bsn,
                             int* __restrict__ rsp, int* __restrict__ rsn) {
  __shared__ int sp_[128], sn_[128];
  const int t = threadIdx.x;
  sp_[t] = (t < NSB) ? bsp[t] : 0;
  sn_[t] = (t < NSB) ? bsn[t] : 0;
  __syncthreads();
  for (int off = 1; off < 128; off <<= 1) {
    const int ap = (t >= off) ? sp_[t - off] : 0;
    const int an = (t >= off) ? sn_[t - off] : 0;
    __syncthreads();
    sp_[t] += ap; sn_[t] += an;
    __syncthreads();
  }
  if (t < NSB) { bsp[t] = (t == 0) ? 0 : sp_[t - 1]; bsn[t] = (t == 0) ? 0 : sn_[t - 1]; }
  if (t == 127) { rsp[N_NODES] = sp_[127]; rsn[N_NODES] = sn_[127]; }
}

// ---------------- scan phase 3: block scan + offset -> row starts + rdeg ----------------
__global__ __launch_bounds__(SB) void scan3_kernel(const int* __restrict__ cntp,
                                                   const int* __restrict__ cntn,
                                                   const int* __restrict__ bsp,
                                                   const int* __restrict__ bsn,
                                                   int* __restrict__ rsp, int* __restrict__ rsn,
                                                   float* __restrict__ rdeg) {
  __shared__ int sp_[SB], sn_[SB];
  const int t = threadIdx.x;
  const int i = blockIdx.x * SB + t;
  const int cp = (i < N_NODES) ? cntp[i] : 0;
  const int cn = (i < N_NODES) ? cntn[i] : 0;
  sp_[t] = cp; sn_[t] = cn;
  __syncthreads();
  for (int off = 1; off < SB; off <<= 1) {
    const int ap = (t >= off) ? sp_[t - off] : 0;
    const int an = (t >= off) ? sn_[t - off] : 0;
    __syncthreads();
    sp_[t] += ap; sn_[t] += an;
    __syncthreads();
  }
  if (i < N_NODES) {
    rsp[i] = bsp[blockIdx.x] + sp_[t] - cp;   // exclusive
    rsn[i] = bsn[blockIdx.x] + sn_[t] - cn;
    rdeg[i] = 1.f / sqrtf((float)(cp + cn));
  }
}

// ---------------- scatter into CSR with finalized coeff (recomputes sigmoid) ----------------
__global__ void scatter_kernel(const int* __restrict__ adjp, const int* __restrict__ adjn,
                               const float* __restrict__ spA, const float* __restrict__ dpA,
                               const float* __restrict__ snA, const float* __restrict__ dnA,
                               const float* __restrict__ rdeg,
                               const int* __restrict__ rsp, const int* __restrict__ rsn,
                               int* __restrict__ curp, int* __restrict__ curn,
                               int* __restrict__ colp, float* __restrict__ cfp,
                               int* __restrict__ coln, float* __restrict__ cfn) {
  const int g = blockIdx.x * blockDim.x + threadIdx.x;
  if (g >= 2 * NEDGE) return;
  if (g < NEDGE) {
    const int src = adjp[g], dst = adjp[NEDGE + g];
    const float e = spA[src] + dpA[dst];
    const float l = e > 0.f ? e : 0.2f * e;
    const float c = (1.f / (1.f + expf(-l))) * rdeg[src] * rdeg[dst];
    const int p = rsp[src] + atomicAdd(&curp[src], 1);
    colp[p] = dst; cfp[p] = c;
  } else {
    const int e2 = g - NEDGE;
    const int src = adjn[e2], dst = adjn[NEDGE + e2];
    const float e = snA[src] + dnA[dst];
    const float l = e > 0.f ? e : 0.2f * e;
    const float c = (1.f / (1.f + expf(-l))) * rdeg[src] * rdeg[dst];
    const int p = rsn[src] + atomicAdd(&curn[src], 1);
    coln[p] = dst; cfn[p] = c;
  }
}

// ---- aggregate: 2 rows/block, 2 waves/row (pos & neg in parallel), 4-deep gather pipeline ----
__global__ __launch_bounds__(256) void agg_kernel(
    const unsigned short* __restrict__ H,
    const int* __restrict__ rsp, const int* __restrict__ colp, const float* __restrict__ cfp,
    const int* __restrict__ rsn, const int* __restrict__ coln, const float* __restrict__ cfn,
    const float* __restrict__ bias, float* __restrict__ out) {
  __shared__ float4 sneg[2][64];
  const int wave = threadIdx.x >> 6, lane = threadIdx.x & 63;
  const int r = wave >> 1;                 // 0..1  local row
  const int sign = wave & 1;               // 0 = pos, 1 = neg
  const int i = blockIdx.x * 2 + r;
  const int* __restrict__ rs  = sign ? rsn : rsp;
  const int* __restrict__ col = sign ? coln : colp;
  const float* __restrict__ cf = sign ? cfn : cfp;
  const unsigned short* __restrict__ Hb = H + sign * 256 + (size_t)lane * 4;
  const int beg = rs[i], end = rs[i + 1];
  float4 a0 = {0,0,0,0}, a1 = {0,0,0,0}, a2 = {0,0,0,0}, a3 = {0,0,0,0};
  int e = beg;
  for (; e + 4 <= end; e += 4) {
    const int c0 = col[e], c1 = col[e + 1], c2 = col[e + 2], c3 = col[e + 3];
    const float f0 = cf[e], f1 = cf[e + 1], f2 = cf[e + 2], f3 = cf[e + 3];
    const ushort4 h0 = *(const ushort4*)(Hb + (size_t)c0 * 512);
    const ushort4 h1 = *(const ushort4*)(Hb + (size_t)c1 * 512);
    const ushort4 h2 = *(const ushort4*)(Hb + (size_t)c2 * 512);
    const ushort4 h3 = *(const ushort4*)(Hb + (size_t)c3 * 512);
    a0.x += f0 * bf2f(h0.x); a0.y += f0 * bf2f(h0.y); a0.z += f0 * bf2f(h0.z); a0.w += f0 * bf2f(h0.w);
    a1.x += f1 * bf2f(h1.x); a1.y += f1 * bf2f(h1.y); a1.z += f1 * bf2f(h1.z); a1.w += f1 * bf2f(h1.w);
    a2.x += f2 * bf2f(h2.x); a2.y += f2 * bf2f(h2.y); a2.z += f2 * bf2f(h2.z); a2.w += f2 * bf2f(h2.w);
    a3.x += f3 * bf2f(h3.x); a3.y += f3 * bf2f(h3.y); a3.z += f3 * bf2f(h3.z); a3.w += f3 * bf2f(h3.w);
  }
  for (; e < end; ++e) {
    const int c0 = col[e];
    const float f0 = cf[e];
    const ushort4 h0 = *(const ushort4*)(Hb + (size_t)c0 * 512);
    a0.x += f0 * bf2f(h0.x); a0.y += f0 * bf2f(h0.y); a0.z += f0 * bf2f(h0.z); a0.w += f0 * bf2f(h0.w);
  }
  float4 a;
  a.x = (a0.x + a1.x) + (a2.x + a3.x);
  a.y = (a0.y + a1.y) + (a2.y + a3.y);
  a.z = (a0.z + a1.z) + (a2.z + a3.z);
  a.w = (a0.w + a1.w) + (a2.w + a3.w);
  if (sign) sneg[r][lane] = a;
  __syncthreads();
  if (sign) {
    ((float4*)(out + (size_t)2 * N_NODES * 256))[(size_t)i * 64 + lane] = a;   // h_agg_neg
  } else {
    const float4 an = sneg[r][lane];
    const float4 bv = ((const float4*)bias)[lane];
    float4 o;
    o.x = a.x - an.x + bv.x; o.y = a.y - an.y + bv.y;
    o.z = a.z - an.z + bv.z; o.w = a.w - an.w + bv.w;
    ((float4*)out)[(size_t)i * 64 + lane] = o;                                  // output
    ((float4*)(out + (size_t)N_NODES * 256))[(size_t)i * 64 + lane] = a;        // h_agg_pos
  }
}

extern "C" void kernel_launch(void* const* d_in, const int* in_sizes, int n_in,
                              void* d_out, int out_size, void* d_ws, size_t ws_size,
                              hipStream_t stream) {
  const float* node    = (const float*)d_in[0];
  const int*   adjp    = (const int*)d_in[1];
  const int*   adjn    = (const int*)d_in[2];
  const float* basis   = (const float*)d_in[3];
  const float* att     = (const float*)d_in[4];
  const float* mapping = (const float*)d_in[5];
  const float* bias    = (const float*)d_in[6];
  const float* theta1  = (const float*)d_in[7];
  const float* b1      = (const float*)d_in[8];
  const float* theta2  = (const float*)d_in[9];
  const float* b2      = (const float*)d_in[10];
  float* out = (float*)d_out;

  size_t off = 0;
  char* wsb = (char*)d_ws;
  auto alloc = [&](size_t bytes) -> char* {
    char* p = wsb + off;
    off = (off + bytes + 255) & ~(size_t)255;
    return p;
  };
  unsigned short* A16 = (unsigned short*)alloc((size_t)N_NODES * 256 * 2);
  unsigned short* H   = (unsigned short*)alloc((size_t)N_NODES * 512 * 2);
  unsigned short* Wt  = (unsigned short*)alloc(512 * 256 * 2);
  float* biasvec = (float*)alloc(512 * 4);
  float* sdbuf = (float*)alloc((size_t)4 * N_NODES * 4);  // sp | dp | sn | dn (one memset)
  float* spA = sdbuf, *dpA = sdbuf + N_NODES, *snA = sdbuf + 2 * N_NODES, *dnA = sdbuf + 3 * N_NODES;
  float* rdeg = (float*)alloc(N_NODES * 4);
  int* cnt2 = (int*)alloc((size_t)2 * N_NODES * 4);       // cntp | cntn
  int* cntp = cnt2, *cntn = cnt2 + N_NODES;
  int* cur2 = (int*)alloc((size_t)2 * N_NODES * 4);       // curp | curn
  int* curp = cur2, *curn = cur2 + N_NODES;
  int* rsp = (int*)alloc((N_NODES + 1) * 4);
  int* rsn = (int*)alloc((N_NODES + 1) * 4);
  int* bsp = (int*)alloc(NSB * 4);
  int* bsn = (int*)alloc(NSB * 4);
  int*   colp = (int*)alloc((size_t)NEDGE * 4);
  float* cfp  = (float*)alloc((size_t)NEDGE * 4);
  int*   coln = (int*)alloc((size_t)NEDGE * 4);
  float* cfn  = (float*)alloc((size_t)NEDGE * 4);

  hipMemsetAsync(sdbuf, 0, (size_t)4 * N_NODES * 4, stream);
  hipMemsetAsync(cnt2, 0, (size_t)2 * N_NODES * 4, stream);
  hipMemsetAsync(cur2, 0, (size_t)2 * N_NODES * 4, stream);

  prep_kernel<<<512, 256, 0, stream>>>(basis, att, theta1, theta2, b1, b2, Wt, biasvec);
  cast_kernel<<<2048, 256, 0, stream>>>(node, A16);
  gemm_kernel<<<dim3(4, 391), 256, 0, stream>>>(A16, Wt, biasvec, mapping, H, spA, dpA, snA, dnA);
  count_kernel<<<(2 * NEDGE) / 256, 256, 0, stream>>>(adjp, adjn, cntp, cntn);
  scan1_kernel<<<NSB, SB, 0, stream>>>(cntp, cntn, bsp, bsn);
  scan2_kernel<<<1, 128, 0, stream>>>(bsp, bsn, rsp, rsn);
  scan3_kernel<<<NSB, SB, 0, stream>>>(cntp, cntn, bsp, bsn, rsp, rsn, rdeg);
  scatter_kernel<<<(2 * NEDGE) / 256, 256, 0, stream>>>(adjp, adjn, spA, dpA, snA, dnA, rdeg,
                                                        rsp, rsn, curp, curn, colp, cfp, coln, cfn);
  agg_kernel<<<N_NODES / 2, 256, 0, stream>>>(H, rsp, colp, cfp, rsn, coln, cfn, bias, out);
}

// Round 5
// 246.858 us; speedup vs baseline: 1.8751x; 1.0784x over previous
//
#include <hip/hip_runtime.h>

#define N_NODES 50000
#define NEDGE   400000
#define SB      512
#define NSB     ((N_NODES + SB - 1) / SB)   // 98 scan blocks

typedef __bf16 bf16x8 __attribute__((ext_vector_type(8)));
typedef float  f32x4  __attribute__((ext_vector_type(4)));
typedef unsigned short u16x8 __attribute__((ext_vector_type(8)));

#define GLDS16(gp, lp) \
  __builtin_amdgcn_global_load_lds((const __attribute__((address_space(1))) void*)(gp), \
                                   (__attribute__((address_space(3))) void*)(lp), 16, 0, 0)

static __device__ __forceinline__ unsigned short f2bf(float f) {
  unsigned u = __float_as_uint(f);
  unsigned r = (u + 0x7fffu + ((u >> 16) & 1u)) >> 16;   // RNE
  return (unsigned short)r;
}
static __device__ __forceinline__ float bf2f(unsigned short v) {
  return __uint_as_float((unsigned)v << 16);
}

// ---------------- prep: Wt[r*256+n][k] = (Wr[r] @ theta_r)[k][n], bf16; biasvec ----------------
__global__ void prep_kernel(const float* __restrict__ basis, const float* __restrict__ att,
                            const float* __restrict__ theta1, const float* __restrict__ theta2,
                            const float* __restrict__ bias1, const float* __restrict__ bias2,
                            unsigned short* __restrict__ Wt, float* __restrict__ biasvec) {
  const int bid = blockIdx.x;            // 0..511 : r*256 + k
  const int r = bid >> 8, k = bid & 255;
  const int n = threadIdx.x;             // 0..255
  const float a0 = att[r * 2 + 0], a1 = att[r * 2 + 1];
  const float* th = (r == 0) ? theta1 : theta2;
  float acc = 0.f;
  for (int j = 0; j < 256; ++j) {
    const float wr = a0 * basis[k * 256 + j] + a1 * basis[65536 + k * 256 + j]; // uniform: scalar load
    acc += wr * th[j * 256 + n];                                                // coalesced
  }
  Wt[(size_t)(r * 256 + n) * 256 + k] = f2bf(acc);
  if (k == 0) biasvec[r * 256 + n] = (r == 0) ? bias1[n] : bias2[n];
}

// ---------------- cast node_reps f32 -> bf16 ----------------
__global__ void cast_kernel(const float* __restrict__ in, unsigned short* __restrict__ out) {
  const long total = (long)N_NODES * 256 / 4;
  long idx = (long)blockIdx.x * blockDim.x + threadIdx.x;
  const long stride = (long)gridDim.x * blockDim.x;
  for (; idx < total; idx += stride) {
    const f32x4 v = __builtin_nontemporal_load(&((const f32x4*)in)[idx]);  // never re-read
    ushort4 o;
    o.x = f2bf(v.x); o.y = f2bf(v.y); o.z = f2bf(v.z); o.w = f2bf(v.w);
    ((ushort4*)out)[idx] = o;
  }
}

// ---- GEMM: H[M][512] = A[M][256] @ W[256][512] + biasvec, bf16 MFMA; fused per-node dots ----
// sdbuf layout: [(sign*2 + type)*4 + slice][N]  type: 0 = s (w_src dot), 1 = d (w_dst dot)
__global__ __launch_bounds__(256) void gemm_kernel(
    const unsigned short* __restrict__ A,    // [M][256] bf16
    const unsigned short* __restrict__ Wt,   // [512][256] bf16 (N-major, i.e. B^T)
    const float* __restrict__ biasvec,       // [512]
    const float* __restrict__ mapping,       // [512]: w_src | w_dst
    unsigned short* __restrict__ H,          // [M][512] bf16
    float* __restrict__ sdbuf) {
  __shared__ unsigned short smem[128 * 136];   // main loop: sA(8192) + sB(8192); epilogue: 128x136 tile
  unsigned short* sA = smem;
  unsigned short* sB = smem + 8192;
  const int tid = threadIdx.x;
  const int wave = tid >> 6, lane = tid & 63;
  const int wm = wave >> 1, wn = wave & 1;
  const int m0 = blockIdx.y * 128;
  const int n0 = blockIdx.x * 128;

  f32x4 acc[4][4];
#pragma unroll
  for (int a = 0; a < 4; ++a)
#pragma unroll
    for (int b = 0; b < 4; ++b) acc[a][b] = (f32x4){0.f, 0.f, 0.f, 0.f};

  // staging geometry: chunk = 8 rows x 64 k (1KB). lane -> (row srow, swizzled k)
  const int srow = lane >> 3;                      // 0..7
  const int skel = ((lane & 7) ^ srow) << 3;       // pre-swizzled source k element

  for (int ks = 0; ks < 4; ++ks) {
    const int kg = ks * 64 + skel;
#pragma unroll
    for (int c = 0; c < 4; ++c) {
      const int chunk = wave * 4 + c;              // 0..15
      const int row = chunk * 8 + srow;            // 0..127
      int rowg = m0 + row;
      rowg = rowg < N_NODES ? rowg : N_NODES - 1;  // clamp (writes are guarded)
      GLDS16(A + (size_t)rowg * 256 + kg, sA + chunk * 512);
      GLDS16(Wt + (size_t)(n0 + row) * 256 + kg, sB + chunk * 512);
    }
    __syncthreads();
#pragma unroll
    for (int kk = 0; kk < 2; ++kk) {
      const int kb = (kk * 32 + ((lane >> 4) << 3)) << 1;  // logical k byte offset in row
      bf16x8 af[4], bfr[4];
#pragma unroll
      for (int m16 = 0; m16 < 4; ++m16) {
        const int row = wm * 64 + m16 * 16 + (lane & 15);
        af[m16] = *(const bf16x8*)((const char*)sA + row * 128 + (kb ^ ((row & 7) << 4)));
      }
#pragma unroll
      for (int n16 = 0; n16 < 4; ++n16) {
        const int col = wn * 64 + n16 * 16 + (lane & 15);
        bfr[n16] = *(const bf16x8*)((const char*)sB + col * 128 + (kb ^ ((col & 7) << 4)));
      }
#pragma unroll
      for (int m16 = 0; m16 < 4; ++m16)
#pragma unroll
        for (int n16 = 0; n16 < 4; ++n16)
          acc[m16][n16] = __builtin_amdgcn_mfma_f32_16x16x32_bf16(af[m16], bfr[n16], acc[m16][n16], 0, 0, 0);
    }
    __syncthreads();
  }

  // ---- epilogue: dots to partial slices (non-atomic) + bf16 tile via LDS -> coalesced H write ----
  const bool sgn = (n0 >= 256);
  const int nb = (sgn ? (n0 - 256) : n0) >> 7;   // 0..1
  const int slice = nb * 2 + wn;                 // 0..3
  float* __restrict__ sS = sdbuf + ((size_t)((sgn ? 2 : 0) + 0) * 4 + slice) * N_NODES;
  float* __restrict__ sD = sdbuf + ((size_t)((sgn ? 2 : 0) + 1) * 4 + slice) * N_NODES;
  float bv[4], wsv[4], wdv[4];
#pragma unroll
  for (int n16 = 0; n16 < 4; ++n16) {
    const int colg = n0 + wn * 64 + n16 * 16 + (lane & 15);
    bv[n16] = biasvec[colg];
    const int cm = colg & 255;
    wsv[n16] = mapping[cm];
    wdv[n16] = mapping[256 + cm];
  }
  // C/D layout: col=lane&15, row=(lane>>4)*4+j  [m89-verified]
#pragma unroll
  for (int m16 = 0; m16 < 4; ++m16) {
    const int rowb = wm * 64 + m16 * 16 + ((lane >> 4) << 2);   // block-local row
#pragma unroll
    for (int j = 0; j < 4; ++j) {
      const int rowl = rowb + j;
      float vs = 0.f, vd = 0.f;
#pragma unroll
      for (int n16 = 0; n16 < 4; ++n16) {
        const float v = acc[m16][n16][j] + bv[n16];
        const int coll = wn * 64 + n16 * 16 + (lane & 15);
        smem[rowl * 136 + coll] = f2bf(v);
        vs += v * wsv[n16];
        vd += v * wdv[n16];
      }
#pragma unroll
      for (int off = 1; off < 16; off <<= 1) { vs += __shfl_xor(vs, off); vd += __shfl_xor(vd, off); }
      const int rowg = m0 + rowl;
      if ((lane & 15) == 0 && rowg < N_NODES) { sS[rowg] = vs; sD[rowg] = vd; }
    }
  }
  __syncthreads();
#pragma unroll
  for (int it = 0; it < 8; ++it) {
    const int row = it * 16 + (tid >> 4);
    const int c8 = (tid & 15) * 8;
    const int rowg = m0 + row;
    if (rowg < N_NODES) {
      const u16x8 v = *(const u16x8*)(smem + row * 136 + c8);
      *(u16x8*)(&H[(size_t)rowg * 512 + n0 + c8]) = v;
    }
  }
}

// ---------------- edges: per-row counts only ----------------
__global__ void count_kernel(const int* __restrict__ adjp, const int* __restrict__ adjn,
                             int* __restrict__ cntp, int* __restrict__ cntn) {
  const int g = blockIdx.x * blockDim.x + threadIdx.x;
  if (g >= 2 * NEDGE) return;
  if (g < NEDGE) atomicAdd(&cntp[adjp[g]], 1);
  else           atomicAdd(&cntn[adjn[g - NEDGE]], 1);
}

// ---------------- scan phase 1: per-block partial sums ----------------
__global__ __launch_bounds__(SB) void scan1_kernel(const int* __restrict__ cntp,
                                                   const int* __restrict__ cntn,
                                                   int* __restrict__ bsp, int* __restrict__ bsn) {
  __shared__ int lp[SB / 64], ln[SB / 64];
  const int i = blockIdx.x * SB + threadIdx.x;
  int vp = (i < N_NODES) ? cntp[i] : 0;
  int vn = (i < N_NODES) ? cntn[i] : 0;
#pragma unroll
  for (int off = 1; off < 64; off <<= 1) { vp += __shfl_xor(vp, off); vn += __shfl_xor(vn, off); }
  const int wave = threadIdx.x >> 6, lane = threadIdx.x & 63;
  if (lane == 0) { lp[wave] = vp; ln[wave] = vn; }
  __syncthreads();
  if (threadIdx.x == 0) {
    int ap = 0, an = 0;
#pragma unroll
    for (int w = 0; w < SB / 64; ++w) { ap += lp[w]; an += ln[w]; }
    bsp[blockIdx.x] = ap; bsn[blockIdx.x] = an;
  }
}

// ---------------- scan phase 2: scan the 98 block sums (one small block) ----------------
__global__ void scan2_kernel(int* __restrict__ bsp, int* __restrict__ bsn,
                             int* __restrict__ rsp, int* __restrict__ rsn) {
  __shared__ int sp_[128], sn_[128];
  const int t = threadIdx.x;
  sp_[t] = (t < NSB) ? bsp[t] : 0;
  sn_[t] = (t < NSB) ? bsn[t] : 0;
  __syncthreads();
  for (int off = 1; off < 128; off <<= 1) {
    const int ap = (t >= off) ? sp_[t - off] : 0;
    const int an = (t >= off) ? sn_[t - off] : 0;
    __syncthreads();
    sp_[t] += ap; sn_[t] += an;
    __syncthreads();
  }
  if (t < NSB) { bsp[t] = (t == 0) ? 0 : sp_[t - 1]; bsn[t] = (t == 0) ? 0 : sn_[t - 1]; }
  if (t == 127) { rsp[N_NODES] = sp_[127]; rsn[N_NODES] = sn_[127]; }
}

// ------- scan phase 3: block scan + offset -> row starts + rdeg + scatter cursors -------
__global__ __launch_bounds__(SB) void scan3_kernel(const int* __restrict__ cntp,
                                                   const int* __restrict__ cntn,
                                                   const int* __restrict__ bsp,
                                                   const int* __restrict__ bsn,
                                                   int* __restrict__ rsp, int* __restrict__ rsn,
                                                   int* __restrict__ curp, int* __restrict__ curn,
                                                   float* __restrict__ rdeg) {
  __shared__ int sp_[SB], sn_[SB];
  const int t = threadIdx.x;
  const int i = blockIdx.x * SB + t;
  const int cp = (i < N_NODES) ? cntp[i] : 0;
  const int cn = (i < N_NODES) ? cntn[i] : 0;
  sp_[t] = cp; sn_[t] = cn;
  __syncthreads();
  for (int off = 1; off < SB; off <<= 1) {
    const int ap = (t >= off) ? sp_[t - off] : 0;
    const int an = (t >= off) ? sn_[t - off] : 0;
    __syncthreads();
    sp_[t] += ap; sn_[t] += an;
    __syncthreads();
  }
  if (i < N_NODES) {
    const int rp = bsp[blockIdx.x] + sp_[t] - cp;   // exclusive
    const int rn = bsn[blockIdx.x] + sn_[t] - cn;
    rsp[i] = rp; curp[i] = rp;
    rsn[i] = rn; curn[i] = rn;
    rdeg[i] = 1.f / sqrtf((float)(cp + cn));
  }
}

// ------- scatter into CSR with finalized coeff (recomputes sigmoid from partial slices) -------
__global__ void scatter_kernel(const int* __restrict__ adjp, const int* __restrict__ adjn,
                               const float* __restrict__ sdbuf,
                               const float* __restrict__ rdeg,
                               int* __restrict__ curp, int* __restrict__ curn,
                               int* __restrict__ colp, float* __restrict__ cfp,
                               int* __restrict__ coln, float* __restrict__ cfn) {
  const int g = blockIdx.x * blockDim.x + threadIdx.x;
  if (g >= 2 * NEDGE) return;
  const bool neg = (g >= NEDGE);
  const int e2 = neg ? g - NEDGE : g;
  const int* __restrict__ adj = neg ? adjn : adjp;
  const float* __restrict__ Sb = sdbuf + (size_t)(neg ? 8 : 0) * N_NODES;
  const float* __restrict__ Db = sdbuf + (size_t)(neg ? 12 : 4) * N_NODES;
  int* __restrict__ cur = neg ? curn : curp;
  int* __restrict__ col = neg ? coln : colp;
  float* __restrict__ cf = neg ? cfn : cfp;
  const int src = adj[e2], dst = adj[NEDGE + e2];
  float e = 0.f;
#pragma unroll
  for (int sl = 0; sl < 4; ++sl) e += Sb[(size_t)sl * N_NODES + src] + Db[(size_t)sl * N_NODES + dst];
  const float l = e > 0.f ? e : 0.2f * e;
  const float c = (1.f / (1.f + expf(-l))) * rdeg[src] * rdeg[dst];
  const int p = atomicAdd(&cur[src], 1);
  col[p] = dst; cf[p] = c;
}

// ---- aggregate: 2 rows/block, 2 waves/row (pos & neg in parallel), shfl-broadcast edges ----
__global__ __launch_bounds__(256) void agg_kernel(
    const unsigned short* __restrict__ H,
    const int* __restrict__ rsp, const int* __restrict__ colp, const float* __restrict__ cfp,
    const int* __restrict__ rsn, const int* __restrict__ coln, const float* __restrict__ cfn,
    const float* __restrict__ bias, float* __restrict__ out) {
  __shared__ f32x4 sneg[2][64];
  const int wave = threadIdx.x >> 6, lane = threadIdx.x & 63;
  const int r = wave >> 1;                 // 0..1  local row
  const int sign = wave & 1;               // 0 = pos, 1 = neg
  const int i = blockIdx.x * 2 + r;
  const int* __restrict__ rs  = sign ? rsn : rsp;
  const int* __restrict__ col = sign ? coln : colp;
  const float* __restrict__ cf = sign ? cfn : cfp;
  const unsigned short* __restrict__ Hb = H + sign * 256 + (size_t)lane * 4;
  const int beg = rs[i], end = rs[i + 1];
  f32x4 a0 = {0,0,0,0}, a1 = {0,0,0,0}, a2 = {0,0,0,0}, a3 = {0,0,0,0};
  for (int chunk = beg; chunk < end; chunk += 64) {
    const int m = (end - chunk < 64) ? end - chunk : 64;
    const int   cv = (lane < m) ? col[chunk + lane] : 0;
    const float fv = (lane < m) ? cf[chunk + lane] : 0.f;
    int k = 0;
    for (; k + 4 <= m; k += 4) {
      const int   c0 = __shfl(cv, k),     c1 = __shfl(cv, k + 1);
      const int   c2 = __shfl(cv, k + 2), c3 = __shfl(cv, k + 3);
      const float f0 = __shfl(fv, k),     f1 = __shfl(fv, k + 1);
      const float f2 = __shfl(fv, k + 2), f3 = __shfl(fv, k + 3);
      const ushort4 h0 = *(const ushort4*)(Hb + (size_t)c0 * 512);
      const ushort4 h1 = *(const ushort4*)(Hb + (size_t)c1 * 512);
      const ushort4 h2 = *(const ushort4*)(Hb + (size_t)c2 * 512);
      const ushort4 h3 = *(const ushort4*)(Hb + (size_t)c3 * 512);
      a0.x += f0 * bf2f(h0.x); a0.y += f0 * bf2f(h0.y); a0.z += f0 * bf2f(h0.z); a0.w += f0 * bf2f(h0.w);
      a1.x += f1 * bf2f(h1.x); a1.y += f1 * bf2f(h1.y); a1.z += f1 * bf2f(h1.z); a1.w += f1 * bf2f(h1.w);
      a2.x += f2 * bf2f(h2.x); a2.y += f2 * bf2f(h2.y); a2.z += f2 * bf2f(h2.z); a2.w += f2 * bf2f(h2.w);
      a3.x += f3 * bf2f(h3.x); a3.y += f3 * bf2f(h3.y); a3.z += f3 * bf2f(h3.z); a3.w += f3 * bf2f(h3.w);
    }
    for (; k < m; ++k) {
      const int   c0 = __shfl(cv, k);
      const float f0 = __shfl(fv, k);
      const ushort4 h0 = *(const ushort4*)(Hb + (size_t)c0 * 512);
      a0.x += f0 * bf2f(h0.x); a0.y += f0 * bf2f(h0.y); a0.z += f0 * bf2f(h0.z); a0.w += f0 * bf2f(h0.w);
    }
  }
  f32x4 a = (a0 + a1) + (a2 + a3);
  if (sign) sneg[r][lane] = a;
  __syncthreads();
  if (sign) {
    __builtin_nontemporal_store(a, ((f32x4*)(out + (size_t)2 * N_NODES * 256)) + (size_t)i * 64 + lane);
  } else {
    const f32x4 an = sneg[r][lane];
    const f32x4 bv = ((const f32x4*)bias)[lane];
    const f32x4 o = a - an + bv;
    __builtin_nontemporal_store(o, ((f32x4*)out) + (size_t)i * 64 + lane);
    __builtin_nontemporal_store(a, ((f32x4*)(out + (size_t)N_NODES * 256)) + (size_t)i * 64 + lane);
  }
}

extern "C" void kernel_launch(void* const* d_in, const int* in_sizes, int n_in,
                              void* d_out, int out_size, void* d_ws, size_t ws_size,
                              hipStream_t stream) {
  const float* node    = (const float*)d_in[0];
  const int*   adjp    = (const int*)d_in[1];
  const int*   adjn    = (const int*)d_in[2];
  const float* basis   = (const float*)d_in[3];
  const float* att     = (const float*)d_in[4];
  const float* mapping = (const float*)d_in[5];
  const float* bias    = (const float*)d_in[6];
  const float* theta1  = (const float*)d_in[7];
  const float* b1      = (const float*)d_in[8];
  const float* theta2  = (const float*)d_in[9];
  const float* b2      = (const float*)d_in[10];
  float* out = (float*)d_out;

  size_t off = 0;
  char* wsb = (char*)d_ws;
  auto alloc = [&](size_t bytes) -> char* {
    char* p = wsb + off;
    off = (off + bytes + 255) & ~(size_t)255;
    return p;
  };
  unsigned short* A16 = (unsigned short*)alloc((size_t)N_NODES * 256 * 2);
  unsigned short* H   = (unsigned short*)alloc((size_t)N_NODES * 512 * 2);
  unsigned short* Wt  = (unsigned short*)alloc(512 * 256 * 2);
  float* biasvec = (float*)alloc(512 * 4);
  float* sdbuf = (float*)alloc((size_t)16 * N_NODES * 4);  // 16 partial-dot slices
  float* rdeg = (float*)alloc(N_NODES * 4);
  int* cnt2 = (int*)alloc((size_t)2 * N_NODES * 4);        // cntp | cntn (one memset)
  int* cntp = cnt2, *cntn = cnt2 + N_NODES;
  int* cur2 = (int*)alloc((size_t)2 * N_NODES * 4);        // initialized by scan3
  int* curp = cur2, *curn = cur2 + N_NODES;
  int* rsp = (int*)alloc((N_NODES + 1) * 4);
  int* rsn = (int*)alloc((N_NODES + 1) * 4);
  int* bsp = (int*)alloc(NSB * 4);
  int* bsn = (int*)alloc(NSB * 4);
  int*   colp = (int*)alloc((size_t)NEDGE * 4);
  float* cfp  = (float*)alloc((size_t)NEDGE * 4);
  int*   coln = (int*)alloc((size_t)NEDGE * 4);
  float* cfn  = (float*)alloc((size_t)NEDGE * 4);

  (void)hipMemsetAsync(cnt2, 0, (size_t)2 * N_NODES * 4, stream);

  prep_kernel<<<512, 256, 0, stream>>>(basis, att, theta1, theta2, b1, b2, Wt, biasvec);
  cast_kernel<<<2048, 256, 0, stream>>>(node, A16);
  gemm_kernel<<<dim3(4, 391), 256, 0, stream>>>(A16, Wt, biasvec, mapping, H, sdbuf);
  count_kernel<<<(2 * NEDGE) / 256, 256, 0, stream>>>(adjp, adjn, cntp, cntn);
  scan1_kernel<<<NSB, SB, 0, stream>>>(cntp, cntn, bsp, bsn);
  scan2_kernel<<<1, 128, 0, stream>>>(bsp, bsn, rsp, rsn);
  scan3_kernel<<<NSB, SB, 0, stream>>>(cntp, cntn, bsp, bsn, rsp, rsn, curp, curn, rdeg);
  scatter_kernel<<<(2 * NEDGE) / 256, 256, 0, stream>>>(adjp, adjn, sdbuf, rdeg,
                                                        curp, curn, colp, cfp, coln, cfn);
  agg_kernel<<<N_NODES / 2, 256, 0, stream>>>(H, rsp, colp, cfp, rsn, coln, cfn, bias, out);
}

// Round 6
// 227.411 us; speedup vs baseline: 2.0354x; 1.0855x over previous
//
#include <hip/hip_runtime.h>

#define N_NODES 50000
#define NEDGE   400000
#define SB      512
#define NSB     ((N_NODES + SB - 1) / SB)   // 98 scan blocks

typedef __bf16 bf16x8 __attribute__((ext_vector_type(8)));
typedef float  f32x4  __attribute__((ext_vector_type(4)));
typedef unsigned short u16x8 __attribute__((ext_vector_type(8)));
typedef int    i32x2  __attribute__((ext_vector_type(2)));

#define GLDS16(gp, lp) \
  __builtin_amdgcn_global_load_lds((const __attribute__((address_space(1))) void*)(gp), \
                                   (__attribute__((address_space(3))) void*)(lp), 16, 0, 0)

static __device__ __forceinline__ unsigned short f2bf(float f) {
  unsigned u = __float_as_uint(f);
  unsigned r = (u + 0x7fffu + ((u >> 16) & 1u)) >> 16;   // RNE
  return (unsigned short)r;
}
static __device__ __forceinline__ float bf2f(unsigned short v) {
  return __uint_as_float((unsigned)v << 16);
}

// ---- fused front end: prep (blocks 0..511) | cast (512..2559) | count (2560..5684) ----
// all three are mutually independent; co-resident latency/BW/atomic work
__global__ __launch_bounds__(256) void fused0_kernel(
    const float* __restrict__ basis, const float* __restrict__ att,
    const float* __restrict__ theta1, const float* __restrict__ theta2,
    const float* __restrict__ bias1, const float* __restrict__ bias2,
    unsigned short* __restrict__ Wt, float* __restrict__ biasvec,
    const float* __restrict__ node, unsigned short* __restrict__ A16,
    const int* __restrict__ adjp, const int* __restrict__ adjn,
    int* __restrict__ cntp, int* __restrict__ cntn) {
  const int b = blockIdx.x;
  if (b < 512) {
    // ---- prep: Wt[r*256+n][k] = (Wr[r] @ theta_r)[k][n], bf16 ----
    const int r = b >> 8, k = b & 255;
    const int n = threadIdx.x;
    const float a0 = att[r * 2 + 0], a1 = att[r * 2 + 1];
    const float* th = (r == 0) ? theta1 : theta2;
    float acc = 0.f;
    for (int j = 0; j < 256; ++j) {
      const float wr = a0 * basis[k * 256 + j] + a1 * basis[65536 + k * 256 + j];
      acc += wr * th[j * 256 + n];
    }
    Wt[(size_t)(r * 256 + n) * 256 + k] = f2bf(acc);
    if (k == 0) biasvec[r * 256 + n] = (r == 0) ? bias1[n] : bias2[n];
  } else if (b < 2560) {
    // ---- cast node_reps f32 -> bf16 ----
    const long total = (long)N_NODES * 256 / 4;
    long idx = (long)(b - 512) * 256 + threadIdx.x;
    const long stride = 2048L * 256;
    for (; idx < total; idx += stride) {
      const f32x4 v = __builtin_nontemporal_load(&((const f32x4*)node)[idx]);
      ushort4 o;
      o.x = f2bf(v.x); o.y = f2bf(v.y); o.z = f2bf(v.z); o.w = f2bf(v.w);
      ((ushort4*)A16)[idx] = o;
    }
  } else {
    // ---- count: per-row degree ----
    const int g = (b - 2560) * 256 + threadIdx.x;
    if (g < NEDGE) atomicAdd(&cntp[adjp[g]], 1);
    else if (g < 2 * NEDGE) atomicAdd(&cntn[adjn[g - NEDGE]], 1);
  }
}

// ---- GEMM: H[M][512] = A[M][256] @ W[256][512] + biasvec, bf16 MFMA; fused per-node dots ----
// sdbuf layout: [(sign*2 + type)*4 + slice][N]  type: 0 = s (w_src dot), 1 = d (w_dst dot)
__global__ __launch_bounds__(256) void gemm_kernel(
    const unsigned short* __restrict__ A,    // [M][256] bf16
    const unsigned short* __restrict__ Wt,   // [512][256] bf16 (N-major, i.e. B^T)
    const float* __restrict__ biasvec,       // [512]
    const float* __restrict__ mapping,       // [512]: w_src | w_dst
    unsigned short* __restrict__ H,          // [M][512] bf16
    float* __restrict__ sdbuf) {
  __shared__ unsigned short smem[128 * 136];   // main loop: sA(8192)+sB(8192); epilogue: 128x136
  unsigned short* sA = smem;
  unsigned short* sB = smem + 8192;
  const int tid = threadIdx.x;
  const int wave = tid >> 6, lane = tid & 63;
  const int wm = wave >> 1, wn = wave & 1;
  const int m0 = blockIdx.y * 128;
  const int n0 = blockIdx.x * 128;

  f32x4 acc[4][4];
#pragma unroll
  for (int a = 0; a < 4; ++a)
#pragma unroll
    for (int b = 0; b < 4; ++b) acc[a][b] = (f32x4){0.f, 0.f, 0.f, 0.f};

  const int srow = lane >> 3;                      // 0..7
  const int skel = ((lane & 7) ^ srow) << 3;       // pre-swizzled source k element

  for (int ks = 0; ks < 4; ++ks) {
    const int kg = ks * 64 + skel;
#pragma unroll
    for (int c = 0; c < 4; ++c) {
      const int chunk = wave * 4 + c;              // 0..15
      const int row = chunk * 8 + srow;            // 0..127
      int rowg = m0 + row;
      rowg = rowg < N_NODES ? rowg : N_NODES - 1;  // clamp (writes are guarded)
      GLDS16(A + (size_t)rowg * 256 + kg, sA + chunk * 512);
      GLDS16(Wt + (size_t)(n0 + row) * 256 + kg, sB + chunk * 512);
    }
    __syncthreads();
#pragma unroll
    for (int kk = 0; kk < 2; ++kk) {
      const int kb = (kk * 32 + ((lane >> 4) << 3)) << 1;
      bf16x8 af[4], bfr[4];
#pragma unroll
      for (int m16 = 0; m16 < 4; ++m16) {
        const int row = wm * 64 + m16 * 16 + (lane & 15);
        af[m16] = *(const bf16x8*)((const char*)sA + row * 128 + (kb ^ ((row & 7) << 4)));
      }
#pragma unroll
      for (int n16 = 0; n16 < 4; ++n16) {
        const int col = wn * 64 + n16 * 16 + (lane & 15);
        bfr[n16] = *(const bf16x8*)((const char*)sB + col * 128 + (kb ^ ((col & 7) << 4)));
      }
#pragma unroll
      for (int m16 = 0; m16 < 4; ++m16)
#pragma unroll
        for (int n16 = 0; n16 < 4; ++n16)
          acc[m16][n16] = __builtin_amdgcn_mfma_f32_16x16x32_bf16(af[m16], bfr[n16], acc[m16][n16], 0, 0, 0);
    }
    __syncthreads();
  }

  // ---- epilogue: dots to partial slices (non-atomic) + bf16 tile via LDS -> coalesced H write ----
  const bool sgn = (n0 >= 256);
  const int nb = (sgn ? (n0 - 256) : n0) >> 7;   // 0..1
  const int slice = nb * 2 + wn;                 // 0..3
  float* __restrict__ sS = sdbuf + ((size_t)((sgn ? 2 : 0) + 0) * 4 + slice) * N_NODES;
  float* __restrict__ sD = sdbuf + ((size_t)((sgn ? 2 : 0) + 1) * 4 + slice) * N_NODES;
  float bv[4], wsv[4], wdv[4];
#pragma unroll
  for (int n16 = 0; n16 < 4; ++n16) {
    const int colg = n0 + wn * 64 + n16 * 16 + (lane & 15);
    bv[n16] = biasvec[colg];
    const int cm = colg & 255;
    wsv[n16] = mapping[cm];
    wdv[n16] = mapping[256 + cm];
  }
  // C/D layout: col=lane&15, row=(lane>>4)*4+j  [m89-verified]
#pragma unroll
  for (int m16 = 0; m16 < 4; ++m16) {
    const int rowb = wm * 64 + m16 * 16 + ((lane >> 4) << 2);   // block-local row
#pragma unroll
    for (int j = 0; j < 4; ++j) {
      const int rowl = rowb + j;
      float vs = 0.f, vd = 0.f;
#pragma unroll
      for (int n16 = 0; n16 < 4; ++n16) {
        const float v = acc[m16][n16][j] + bv[n16];
        const int coll = wn * 64 + n16 * 16 + (lane & 15);
        smem[rowl * 136 + coll] = f2bf(v);
        vs += v * wsv[n16];
        vd += v * wdv[n16];
      }
#pragma unroll
      for (int off = 1; off < 16; off <<= 1) { vs += __shfl_xor(vs, off); vd += __shfl_xor(vd, off); }
      const int rowg = m0 + rowl;
      if ((lane & 15) == 0 && rowg < N_NODES) { sS[rowg] = vs; sD[rowg] = vd; }
    }
  }
  __syncthreads();
#pragma unroll
  for (int it = 0; it < 8; ++it) {
    const int row = it * 16 + (tid >> 4);
    const int c8 = (tid & 15) * 8;
    const int rowg = m0 + row;
    if (rowg < N_NODES) {
      const u16x8 v = *(const u16x8*)(smem + row * 136 + c8);
      *(u16x8*)(&H[(size_t)rowg * 512 + n0 + c8]) = v;
    }
  }
}

// ---------------- scan phase 1: per-block partial sums ----------------
__global__ __launch_bounds__(SB) void scan1_kernel(const int* __restrict__ cntp,
                                                   const int* __restrict__ cntn,
                                                   int* __restrict__ bsp, int* __restrict__ bsn) {
  __shared__ int lp[SB / 64], ln[SB / 64];
  const int i = blockIdx.x * SB + threadIdx.x;
  int vp = (i < N_NODES) ? cntp[i] : 0;
  int vn = (i < N_NODES) ? cntn[i] : 0;
#pragma unroll
  for (int off = 1; off < 64; off <<= 1) { vp += __shfl_xor(vp, off); vn += __shfl_xor(vn, off); }
  const int wave = threadIdx.x >> 6, lane = threadIdx.x & 63;
  if (lane == 0) { lp[wave] = vp; ln[wave] = vn; }
  __syncthreads();
  if (threadIdx.x == 0) {
    int ap = 0, an = 0;
#pragma unroll
    for (int w = 0; w < SB / 64; ++w) { ap += lp[w]; an += ln[w]; }
    bsp[blockIdx.x] = ap; bsn[blockIdx.x] = an;
  }
}

// ---------------- scan phase 2: scan the 98 block sums (one small block) ----------------
__global__ void scan2_kernel(int* __restrict__ bsp, int* __restrict__ bsn,
                             int* __restrict__ rsp, int* __restrict__ rsn) {
  __shared__ int sp_[128], sn_[128];
  const int t = threadIdx.x;
  sp_[t] = (t < NSB) ? bsp[t] : 0;
  sn_[t] = (t < NSB) ? bsn[t] : 0;
  __syncthreads();
  for (int off = 1; off < 128; off <<= 1) {
    const int ap = (t >= off) ? sp_[t - off] : 0;
    const int an = (t >= off) ? sn_[t - off] : 0;
    __syncthreads();
    sp_[t] += ap; sn_[t] += an;
    __syncthreads();
  }
  if (t < NSB) { bsp[t] = (t == 0) ? 0 : sp_[t - 1]; bsn[t] = (t == 0) ? 0 : sn_[t - 1]; }
  if (t == 127) { rsp[N_NODES] = sp_[127]; rsn[N_NODES] = sn_[127]; }
}

// -- scan phase 3: block scan + offset -> row starts, cursors, packed nodeinfo {s,d,rdeg} --
__global__ __launch_bounds__(SB) void scan3_kernel(const int* __restrict__ cntp,
                                                   const int* __restrict__ cntn,
                                                   const int* __restrict__ bsp,
                                                   const int* __restrict__ bsn,
                                                   const float* __restrict__ sdbuf,
                                                   int* __restrict__ rsp, int* __restrict__ rsn,
                                                   int* __restrict__ curp, int* __restrict__ curn,
                                                   f32x4* __restrict__ nip, f32x4* __restrict__ nin) {
  __shared__ int sp_[SB], sn_[SB];
  const int t = threadIdx.x;
  const int i = blockIdx.x * SB + t;
  const int cp = (i < N_NODES) ? cntp[i] : 0;
  const int cn = (i < N_NODES) ? cntn[i] : 0;
  sp_[t] = cp; sn_[t] = cn;
  __syncthreads();
  for (int off = 1; off < SB; off <<= 1) {
    const int ap = (t >= off) ? sp_[t - off] : 0;
    const int an = (t >= off) ? sn_[t - off] : 0;
    __syncthreads();
    sp_[t] += ap; sn_[t] += an;
    __syncthreads();
  }
  if (i < N_NODES) {
    const int rp = bsp[blockIdx.x] + sp_[t] - cp;   // exclusive
    const int rn = bsn[blockIdx.x] + sn_[t] - cn;
    rsp[i] = rp; curp[i] = rp;
    rsn[i] = rn; curn[i] = rn;
    const float rdeg = 1.f / sqrtf((float)(cp + cn));
    float sp4 = 0.f, dp4 = 0.f, sn4 = 0.f, dn4 = 0.f;
#pragma unroll
    for (int sl = 0; sl < 4; ++sl) {
      sp4 += sdbuf[(size_t)(0 * 4 + sl) * N_NODES + i];
      dp4 += sdbuf[(size_t)(1 * 4 + sl) * N_NODES + i];
      sn4 += sdbuf[(size_t)(2 * 4 + sl) * N_NODES + i];
      dn4 += sdbuf[(size_t)(3 * 4 + sl) * N_NODES + i];
    }
    nip[i] = (f32x4){sp4, dp4, rdeg, 0.f};
    nin[i] = (f32x4){sn4, dn4, rdeg, 0.f};
  }
}

// -- scatter into CSR: coeff from 2 packed gathers; single 8B packed {dst,coeff} store --
__global__ void scatter_kernel(const int* __restrict__ adjp, const int* __restrict__ adjn,
                               const f32x4* __restrict__ nip, const f32x4* __restrict__ nin,
                               int* __restrict__ curp, int* __restrict__ curn,
                               i32x2* __restrict__ ecp, i32x2* __restrict__ ecn) {
  const int g = blockIdx.x * blockDim.x + threadIdx.x;
  if (g >= 2 * NEDGE) return;
  const bool neg = (g >= NEDGE);
  const int e2 = neg ? g - NEDGE : g;
  const int* __restrict__ adj = neg ? adjn : adjp;
  const f32x4* __restrict__ ni = neg ? nin : nip;
  int* __restrict__ cur = neg ? curn : curp;
  i32x2* __restrict__ ec = neg ? ecn : ecp;
  const int src = adj[e2], dst = adj[NEDGE + e2];
  const f32x4 a = ni[src], b = ni[dst];
  const float e = a.x + b.y;
  const float l = e > 0.f ? e : 0.2f * e;
  const float c = (1.f / (1.f + expf(-l))) * a.z * b.z;
  const int p = atomicAdd(&cur[src], 1);
  i32x2 w; w.x = dst; w.y = __float_as_int(c);
  ec[p] = w;
}

// ---- aggregate: 2 rows/block, 2 waves/row (pos & neg in parallel), shfl-broadcast edges ----
__global__ __launch_bounds__(256) void agg_kernel(
    const unsigned short* __restrict__ H,
    const int* __restrict__ rsp, const i32x2* __restrict__ ecp,
    const int* __restrict__ rsn, const i32x2* __restrict__ ecn,
    const float* __restrict__ bias, float* __restrict__ out) {
  __shared__ f32x4 sneg[2][64];
  const int wave = threadIdx.x >> 6, lane = threadIdx.x & 63;
  const int r = wave >> 1;                 // 0..1  local row
  const int sign = wave & 1;               // 0 = pos, 1 = neg
  const int i = blockIdx.x * 2 + r;
  const int* __restrict__ rs  = sign ? rsn : rsp;
  const i32x2* __restrict__ ec = sign ? ecn : ecp;
  const unsigned short* __restrict__ Hb = H + sign * 256 + (size_t)lane * 4;
  const int beg = rs[i], end = rs[i + 1];
  f32x4 a0 = {0,0,0,0}, a1 = {0,0,0,0}, a2 = {0,0,0,0}, a3 = {0,0,0,0};
  for (int chunk = beg; chunk < end; chunk += 64) {
    const int m = (end - chunk < 64) ? end - chunk : 64;
    i32x2 ev = {0, 0};
    if (lane < m) ev = __builtin_nontemporal_load(&ec[chunk + lane]);  // read-once stream
    const int   cv = ev.x;
    const float fv = __int_as_float(ev.y);
    int k = 0;
    for (; k + 4 <= m; k += 4) {
      const int   c0 = __shfl(cv, k),     c1 = __shfl(cv, k + 1);
      const int   c2 = __shfl(cv, k + 2), c3 = __shfl(cv, k + 3);
      const float f0 = __shfl(fv, k),     f1 = __shfl(fv, k + 1);
      const float f2 = __shfl(fv, k + 2), f3 = __shfl(fv, k + 3);
      const ushort4 h0 = *(const ushort4*)(Hb + (size_t)c0 * 512);
      const ushort4 h1 = *(const ushort4*)(Hb + (size_t)c1 * 512);
      const ushort4 h2 = *(const ushort4*)(Hb + (size_t)c2 * 512);
      const ushort4 h3 = *(const ushort4*)(Hb + (size_t)c3 * 512);
      a0.x += f0 * bf2f(h0.x); a0.y += f0 * bf2f(h0.y); a0.z += f0 * bf2f(h0.z); a0.w += f0 * bf2f(h0.w);
      a1.x += f1 * bf2f(h1.x); a1.y += f1 * bf2f(h1.y); a1.z += f1 * bf2f(h1.z); a1.w += f1 * bf2f(h1.w);
      a2.x += f2 * bf2f(h2.x); a2.y += f2 * bf2f(h2.y); a2.z += f2 * bf2f(h2.z); a2.w += f2 * bf2f(h2.w);
      a3.x += f3 * bf2f(h3.x); a3.y += f3 * bf2f(h3.y); a3.z += f3 * bf2f(h3.z); a3.w += f3 * bf2f(h3.w);
    }
    for (; k < m; ++k) {
      const int   c0 = __shfl(cv, k);
      const float f0 = __shfl(fv, k);
      const ushort4 h0 = *(const ushort4*)(Hb + (size_t)c0 * 512);
      a0.x += f0 * bf2f(h0.x); a0.y += f0 * bf2f(h0.y); a0.z += f0 * bf2f(h0.z); a0.w += f0 * bf2f(h0.w);
    }
  }
  f32x4 a = (a0 + a1) + (a2 + a3);
  if (sign) sneg[r][lane] = a;
  __syncthreads();
  if (sign) {
    __builtin_nontemporal_store(a, ((f32x4*)(out + (size_t)2 * N_NODES * 256)) + (size_t)i * 64 + lane);
  } else {
    const f32x4 an = sneg[r][lane];
    const f32x4 bv = ((const f32x4*)bias)[lane];
    const f32x4 o = a - an + bv;
    __builtin_nontemporal_store(o, ((f32x4*)out) + (size_t)i * 64 + lane);
    __builtin_nontemporal_store(a, ((f32x4*)(out + (size_t)N_NODES * 256)) + (size_t)i * 64 + lane);
  }
}

extern "C" void kernel_launch(void* const* d_in, const int* in_sizes, int n_in,
                              void* d_out, int out_size, void* d_ws, size_t ws_size,
                              hipStream_t stream) {
  const float* node    = (const float*)d_in[0];
  const int*   adjp    = (const int*)d_in[1];
  const int*   adjn    = (const int*)d_in[2];
  const float* basis   = (const float*)d_in[3];
  const float* att     = (const float*)d_in[4];
  const float* mapping = (const float*)d_in[5];
  const float* bias    = (const float*)d_in[6];
  const float* theta1  = (const float*)d_in[7];
  const float* b1      = (const float*)d_in[8];
  const float* theta2  = (const float*)d_in[9];
  const float* b2      = (const float*)d_in[10];
  float* out = (float*)d_out;

  size_t off = 0;
  char* wsb = (char*)d_ws;
  auto alloc = [&](size_t bytes) -> char* {
    char* p = wsb + off;
    off = (off + bytes + 255) & ~(size_t)255;
    return p;
  };
  unsigned short* A16 = (unsigned short*)alloc((size_t)N_NODES * 256 * 2);
  unsigned short* H   = (unsigned short*)alloc((size_t)N_NODES * 512 * 2);
  unsigned short* Wt  = (unsigned short*)alloc(512 * 256 * 2);
  float* biasvec = (float*)alloc(512 * 4);
  float* sdbuf = (float*)alloc((size_t)16 * N_NODES * 4);  // 16 partial-dot slices
  f32x4* nip = (f32x4*)alloc((size_t)N_NODES * 16);        // {s, d, rdeg, _} pos
  f32x4* nin = (f32x4*)alloc((size_t)N_NODES * 16);        // {s, d, rdeg, _} neg
  int* cnt2 = (int*)alloc((size_t)2 * N_NODES * 4);        // cntp | cntn (one memset)
  int* cntp = cnt2, *cntn = cnt2 + N_NODES;
  int* cur2 = (int*)alloc((size_t)2 * N_NODES * 4);        // initialized by scan3
  int* curp = cur2, *curn = cur2 + N_NODES;
  int* rsp = (int*)alloc((N_NODES + 1) * 4);
  int* rsn = (int*)alloc((N_NODES + 1) * 4);
  int* bsp = (int*)alloc(NSB * 4);
  int* bsn = (int*)alloc(NSB * 4);
  i32x2* ecp = (i32x2*)alloc((size_t)NEDGE * 8);           // packed {dst, coeff}
  i32x2* ecn = (i32x2*)alloc((size_t)NEDGE * 8);

  (void)hipMemsetAsync(cnt2, 0, (size_t)2 * N_NODES * 4, stream);

  fused0_kernel<<<512 + 2048 + (2 * NEDGE) / 256, 256, 0, stream>>>(
      basis, att, theta1, theta2, b1, b2, Wt, biasvec, node, A16, adjp, adjn, cntp, cntn);
  gemm_kernel<<<dim3(4, 391), 256, 0, stream>>>(A16, Wt, biasvec, mapping, H, sdbuf);
  scan1_kernel<<<NSB, SB, 0, stream>>>(cntp, cntn, bsp, bsn);
  scan2_kernel<<<1, 128, 0, stream>>>(bsp, bsn, rsp, rsn);
  scan3_kernel<<<NSB, SB, 0, stream>>>(cntp, cntn, bsp, bsn, sdbuf, rsp, rsn, curp, curn, nip, nin);
  scatter_kernel<<<(2 * NEDGE) / 256, 256, 0, stream>>>(adjp, adjn, nip, nin, curp, curn, ecp, ecn);
  agg_kernel<<<N_NODES / 2, 256, 0, stream>>>(H, rsp, ecp, rsn, ecn, bias, out);
}

// Round 7
// 214.504 us; speedup vs baseline: 2.1579x; 1.0602x over previous
//
#include <hip/hip_runtime.h>

#define N_NODES 50000
#define NEDGE   400000
#define SB      512
#define NSB     ((N_NODES + SB - 1) / SB)   // 98 scan blocks
#define H8SCALE 128.0f                       // power-of-2: exactly undone in coeff

typedef __bf16 bf16x8 __attribute__((ext_vector_type(8)));
typedef float  f32x4  __attribute__((ext_vector_type(4)));
typedef float  f32x2  __attribute__((ext_vector_type(2)));
typedef unsigned short u16x8 __attribute__((ext_vector_type(8)));
typedef int    i32x2  __attribute__((ext_vector_type(2)));

#define GLDS16(gp, lp) \
  __builtin_amdgcn_global_load_lds((const __attribute__((address_space(1))) void*)(gp), \
                                   (__attribute__((address_space(3))) void*)(lp), 16, 0, 0)

static __device__ __forceinline__ unsigned short f2bf(float f) {
  unsigned u = __float_as_uint(f);
  unsigned r = (u + 0x7fffu + ((u >> 16) & 1u)) >> 16;   // RNE
  return (unsigned short)r;
}
static __device__ __forceinline__ float bf2f(unsigned short v) {
  return __uint_as_float((unsigned)v << 16);
}

// ---- fused front end: prep (blocks 0..511) | cast (512..2559) | count (2560..5684) ----
__global__ __launch_bounds__(256) void fused0_kernel(
    const float* __restrict__ basis, const float* __restrict__ att,
    const float* __restrict__ theta1, const float* __restrict__ theta2,
    const float* __restrict__ bias1, const float* __restrict__ bias2,
    unsigned short* __restrict__ Wt, float* __restrict__ biasvec,
    const float* __restrict__ node, unsigned short* __restrict__ A16,
    const int* __restrict__ adjp, const int* __restrict__ adjn,
    int* __restrict__ cntp, int* __restrict__ cntn) {
  const int b = blockIdx.x;
  if (b < 512) {
    // ---- prep: Wt[r*256+n][k] = (Wr[r] @ theta_r)[k][n], bf16 ----
    const int r = b >> 8, k = b & 255;
    const int n = threadIdx.x;
    const float a0 = att[r * 2 + 0], a1 = att[r * 2 + 1];
    const float* th = (r == 0) ? theta1 : theta2;
    float acc = 0.f;
    for (int j = 0; j < 256; ++j) {
      const float wr = a0 * basis[k * 256 + j] + a1 * basis[65536 + k * 256 + j];
      acc += wr * th[j * 256 + n];
    }
    Wt[(size_t)(r * 256 + n) * 256 + k] = f2bf(acc);
    if (k == 0) biasvec[r * 256 + n] = (r == 0) ? bias1[n] : bias2[n];
  } else if (b < 2560) {
    // ---- cast node_reps f32 -> bf16 ----
    const long total = (long)N_NODES * 256 / 4;
    long idx = (long)(b - 512) * 256 + threadIdx.x;
    const long stride = 2048L * 256;
    for (; idx < total; idx += stride) {
      const f32x4 v = __builtin_nontemporal_load(&((const f32x4*)node)[idx]);
      ushort4 o;
      o.x = f2bf(v.x); o.y = f2bf(v.y); o.z = f2bf(v.z); o.w = f2bf(v.w);
      ((ushort4*)A16)[idx] = o;
    }
  } else {
    // ---- count: per-row degree ----
    const int g = (b - 2560) * 256 + threadIdx.x;
    if (g < NEDGE) atomicAdd(&cntp[adjp[g]], 1);
    else if (g < 2 * NEDGE) atomicAdd(&cntn[adjn[g - NEDGE]], 1);
  }
}

// ---- GEMM: H8[M][512] = fp8(128 * (A @ W + bias)), bf16 MFMA; fused per-node dots (f32) ----
// sdbuf layout: [(sign*2 + type)*4 + slice][N]  type: 0 = s (w_src dot), 1 = d (w_dst dot)
__global__ __launch_bounds__(256) void gemm_kernel(
    const unsigned short* __restrict__ A,    // [M][256] bf16
    const unsigned short* __restrict__ Wt,   // [512][256] bf16 (N-major, i.e. B^T)
    const float* __restrict__ biasvec,       // [512]
    const float* __restrict__ mapping,       // [512]: w_src | w_dst
    unsigned char* __restrict__ H8,          // [M][512] fp8 e4m3, x128
    float* __restrict__ sdbuf) {
  __shared__ unsigned short smem[128 * 136];   // main loop: sA(8192)+sB(8192); epilogue: 128x136
  unsigned short* sA = smem;
  unsigned short* sB = smem + 8192;
  const int tid = threadIdx.x;
  const int wave = tid >> 6, lane = tid & 63;
  const int wm = wave >> 1, wn = wave & 1;
  const int m0 = blockIdx.y * 128;
  const int n0 = blockIdx.x * 128;

  f32x4 acc[4][4];
#pragma unroll
  for (int a = 0; a < 4; ++a)
#pragma unroll
    for (int b = 0; b < 4; ++b) acc[a][b] = (f32x4){0.f, 0.f, 0.f, 0.f};

  const int srow = lane >> 3;                      // 0..7
  const int skel = ((lane & 7) ^ srow) << 3;       // pre-swizzled source k element

  for (int ks = 0; ks < 4; ++ks) {
    const int kg = ks * 64 + skel;
#pragma unroll
    for (int c = 0; c < 4; ++c) {
      const int chunk = wave * 4 + c;              // 0..15
      const int row = chunk * 8 + srow;            // 0..127
      int rowg = m0 + row;
      rowg = rowg < N_NODES ? rowg : N_NODES - 1;  // clamp (writes are guarded)
      GLDS16(A + (size_t)rowg * 256 + kg, sA + chunk * 512);
      GLDS16(Wt + (size_t)(n0 + row) * 256 + kg, sB + chunk * 512);
    }
    __syncthreads();
#pragma unroll
    for (int kk = 0; kk < 2; ++kk) {
      const int kb = (kk * 32 + ((lane >> 4) << 3)) << 1;
      bf16x8 af[4], bfr[4];
#pragma unroll
      for (int m16 = 0; m16 < 4; ++m16) {
        const int row = wm * 64 + m16 * 16 + (lane & 15);
        af[m16] = *(const bf16x8*)((const char*)sA + row * 128 + (kb ^ ((row & 7) << 4)));
      }
#pragma unroll
      for (int n16 = 0; n16 < 4; ++n16) {
        const int col = wn * 64 + n16 * 16 + (lane & 15);
        bfr[n16] = *(const bf16x8*)((const char*)sB + col * 128 + (kb ^ ((col & 7) << 4)));
      }
#pragma unroll
      for (int m16 = 0; m16 < 4; ++m16)
#pragma unroll
        for (int n16 = 0; n16 < 4; ++n16)
          acc[m16][n16] = __builtin_amdgcn_mfma_f32_16x16x32_bf16(af[m16], bfr[n16], acc[m16][n16], 0, 0, 0);
    }
    __syncthreads();
  }

  // ---- epilogue: f32 dots to partial slices + bf16 tile via LDS -> coalesced fp8 H write ----
  const bool sgn = (n0 >= 256);
  const int nb = (sgn ? (n0 - 256) : n0) >> 7;   // 0..1
  const int slice = nb * 2 + wn;                 // 0..3
  float* __restrict__ sS = sdbuf + ((size_t)((sgn ? 2 : 0) + 0) * 4 + slice) * N_NODES;
  float* __restrict__ sD = sdbuf + ((size_t)((sgn ? 2 : 0) + 1) * 4 + slice) * N_NODES;
  float bv[4], wsv[4], wdv[4];
#pragma unroll
  for (int n16 = 0; n16 < 4; ++n16) {
    const int colg = n0 + wn * 64 + n16 * 16 + (lane & 15);
    bv[n16] = biasvec[colg];
    const int cm = colg & 255;
    wsv[n16] = mapping[cm];
    wdv[n16] = mapping[256 + cm];
  }
  // C/D layout: col=lane&15, row=(lane>>4)*4+j  [m89-verified]
#pragma unroll
  for (int m16 = 0; m16 < 4; ++m16) {
    const int rowb = wm * 64 + m16 * 16 + ((lane >> 4) << 2);   // block-local row
#pragma unroll
    for (int j = 0; j < 4; ++j) {
      const int rowl = rowb + j;
      float vs = 0.f, vd = 0.f;
#pragma unroll
      for (int n16 = 0; n16 < 4; ++n16) {
        const float v = acc[m16][n16][j] + bv[n16];
        const int coll = wn * 64 + n16 * 16 + (lane & 15);
        smem[rowl * 136 + coll] = f2bf(v);
        vs += v * wsv[n16];
        vd += v * wdv[n16];
      }
#pragma unroll
      for (int off = 1; off < 16; off <<= 1) { vs += __shfl_xor(vs, off); vd += __shfl_xor(vd, off); }
      const int rowg = m0 + rowl;
      if ((lane & 15) == 0 && rowg < N_NODES) { sS[rowg] = vs; sD[rowg] = vd; }
    }
  }
  __syncthreads();
#pragma unroll
  for (int it = 0; it < 8; ++it) {
    const int row = it * 16 + (tid >> 4);
    const int c8 = (tid & 15) * 8;
    const int rowg = m0 + row;
    if (rowg < N_NODES) {
      const u16x8 v = *(const u16x8*)(smem + row * 136 + c8);
      float f[8];
#pragma unroll
      for (int q = 0; q < 8; ++q) f[q] = bf2f((unsigned short)v[q]) * H8SCALE;
      int w0 = __builtin_amdgcn_cvt_pk_fp8_f32(f[0], f[1], 0, false);
      w0     = __builtin_amdgcn_cvt_pk_fp8_f32(f[2], f[3], w0, true);
      int w1 = __builtin_amdgcn_cvt_pk_fp8_f32(f[4], f[5], 0, false);
      w1     = __builtin_amdgcn_cvt_pk_fp8_f32(f[6], f[7], w1, true);
      i32x2 o; o.x = w0; o.y = w1;
      *(i32x2*)(&H8[(size_t)rowg * 512 + n0 + c8]) = o;
    }
  }
}

// ---------------- scan phase 1: per-block partial sums ----------------
__global__ __launch_bounds__(SB) void scan1_kernel(const int* __restrict__ cntp,
                                                   const int* __restrict__ cntn,
                                                   int* __restrict__ bsp, int* __restrict__ bsn) {
  __shared__ int lp[SB / 64], ln[SB / 64];
  const int i = blockIdx.x * SB + threadIdx.x;
  int vp = (i < N_NODES) ? cntp[i] : 0;
  int vn = (i < N_NODES) ? cntn[i] : 0;
#pragma unroll
  for (int off = 1; off < 64; off <<= 1) { vp += __shfl_xor(vp, off); vn += __shfl_xor(vn, off); }
  const int wave = threadIdx.x >> 6, lane = threadIdx.x & 63;
  if (lane == 0) { lp[wave] = vp; ln[wave] = vn; }
  __syncthreads();
  if (threadIdx.x == 0) {
    int ap = 0, an = 0;
#pragma unroll
    for (int w = 0; w < SB / 64; ++w) { ap += lp[w]; an += ln[w]; }
    bsp[blockIdx.x] = ap; bsn[blockIdx.x] = an;
  }
}

// ---------------- scan phase 2: scan the 98 block sums (one small block) ----------------
__global__ void scan2_kernel(int* __restrict__ bsp, int* __restrict__ bsn,
                             int* __restrict__ rsp, int* __restrict__ rsn) {
  __shared__ int sp_[128], sn_[128];
  const int t = threadIdx.x;
  sp_[t] = (t < NSB) ? bsp[t] : 0;
  sn_[t] = (t < NSB) ? bsn[t] : 0;
  __syncthreads();
  for (int off = 1; off < 128; off <<= 1) {
    const int ap = (t >= off) ? sp_[t - off] : 0;
    const int an = (t >= off) ? sn_[t - off] : 0;
    __syncthreads();
    sp_[t] += ap; sn_[t] += an;
    __syncthreads();
  }
  if (t < NSB) { bsp[t] = (t == 0) ? 0 : sp_[t - 1]; bsn[t] = (t == 0) ? 0 : sn_[t - 1]; }
  if (t == 127) { rsp[N_NODES] = sp_[127]; rsn[N_NODES] = sn_[127]; }
}

// -- scan phase 3: block scan + offset -> row starts, cursors, packed nodeinfo {s,d,rdeg} --
__global__ __launch_bounds__(SB) void scan3_kernel(const int* __restrict__ cntp,
                                                   const int* __restrict__ cntn,
                                                   const int* __restrict__ bsp,
                                                   const int* __restrict__ bsn,
                                                   const float* __restrict__ sdbuf,
                                                   int* __restrict__ rsp, int* __restrict__ rsn,
                                                   int* __restrict__ curp, int* __restrict__ curn,
                                                   f32x4* __restrict__ nip, f32x4* __restrict__ nin) {
  __shared__ int sp_[SB], sn_[SB];
  const int t = threadIdx.x;
  const int i = blockIdx.x * SB + t;
  const int cp = (i < N_NODES) ? cntp[i] : 0;
  const int cn = (i < N_NODES) ? cntn[i] : 0;
  sp_[t] = cp; sn_[t] = cn;
  __syncthreads();
  for (int off = 1; off < SB; off <<= 1) {
    const int ap = (t >= off) ? sp_[t - off] : 0;
    const int an = (t >= off) ? sn_[t - off] : 0;
    __syncthreads();
    sp_[t] += ap; sn_[t] += an;
    __syncthreads();
  }
  if (i < N_NODES) {
    const int rp = bsp[blockIdx.x] + sp_[t] - cp;   // exclusive
    const int rn = bsn[blockIdx.x] + sn_[t] - cn;
    rsp[i] = rp; curp[i] = rp;
    rsn[i] = rn; curn[i] = rn;
    const float rdeg = 1.f / sqrtf((float)(cp + cn));
    float sp4 = 0.f, dp4 = 0.f, sn4 = 0.f, dn4 = 0.f;
#pragma unroll
    for (int sl = 0; sl < 4; ++sl) {
      sp4 += sdbuf[(size_t)(0 * 4 + sl) * N_NODES + i];
      dp4 += sdbuf[(size_t)(1 * 4 + sl) * N_NODES + i];
      sn4 += sdbuf[(size_t)(2 * 4 + sl) * N_NODES + i];
      dn4 += sdbuf[(size_t)(3 * 4 + sl) * N_NODES + i];
    }
    nip[i] = (f32x4){sp4, dp4, rdeg, 0.f};
    nin[i] = (f32x4){sn4, dn4, rdeg, 0.f};
  }
}

// -- scatter into CSR: coeff (incl. 1/H8SCALE) from 2 packed gathers; 8B {dst,coeff} store --
__global__ void scatter_kernel(const int* __restrict__ adjp, const int* __restrict__ adjn,
                               const f32x4* __restrict__ nip, const f32x4* __restrict__ nin,
                               int* __restrict__ curp, int* __restrict__ curn,
                               i32x2* __restrict__ ecp, i32x2* __restrict__ ecn) {
  const int g = blockIdx.x * blockDim.x + threadIdx.x;
  if (g >= 2 * NEDGE) return;
  const bool neg = (g >= NEDGE);
  const int e2 = neg ? g - NEDGE : g;
  const int* __restrict__ adj = neg ? adjn : adjp;
  const f32x4* __restrict__ ni = neg ? nin : nip;
  int* __restrict__ cur = neg ? curn : curp;
  i32x2* __restrict__ ec = neg ? ecn : ecp;
  const int src = adj[e2], dst = adj[NEDGE + e2];
  const f32x4 a = ni[src], b = ni[dst];
  const float e = a.x + b.y;
  const float l = e > 0.f ? e : 0.2f * e;
  const float c = (1.f / (1.f + expf(-l))) * a.z * b.z * (1.0f / H8SCALE);
  const int p = atomicAdd(&cur[src], 1);
  i32x2 w; w.x = dst; w.y = __float_as_int(c);
  ec[p] = w;
}

// ---- aggregate: 2 rows/block, 2 waves/row (pos & neg in parallel), fp8 H gathers ----
__global__ __launch_bounds__(256) void agg_kernel(
    const unsigned char* __restrict__ H8,
    const int* __restrict__ rsp, const i32x2* __restrict__ ecp,
    const int* __restrict__ rsn, const i32x2* __restrict__ ecn,
    const float* __restrict__ bias, float* __restrict__ out) {
  __shared__ f32x4 sneg[2][64];
  const int wave = threadIdx.x >> 6, lane = threadIdx.x & 63;
  const int r = wave >> 1;                 // 0..1  local row
  const int sign = wave & 1;               // 0 = pos, 1 = neg
  const int i = blockIdx.x * 2 + r;
  const int* __restrict__ rs  = sign ? rsn : rsp;
  const i32x2* __restrict__ ec = sign ? ecn : ecp;
  const unsigned char* __restrict__ Hb = H8 + sign * 256 + (size_t)lane * 4;
  const int beg = rs[i], end = rs[i + 1];
  f32x4 a0 = {0,0,0,0}, a1 = {0,0,0,0}, a2 = {0,0,0,0}, a3 = {0,0,0,0};
  for (int chunk = beg; chunk < end; chunk += 64) {
    const int m = (end - chunk < 64) ? end - chunk : 64;
    i32x2 ev = {0, 0};
    if (lane < m) ev = __builtin_nontemporal_load(&ec[chunk + lane]);  // read-once stream
    const int   cv = ev.x;
    const float fv = __int_as_float(ev.y);
    int k = 0;
    for (; k + 4 <= m; k += 4) {
      const int   c0 = __shfl(cv, k),     c1 = __shfl(cv, k + 1);
      const int   c2 = __shfl(cv, k + 2), c3 = __shfl(cv, k + 3);
      const float f0 = __shfl(fv, k),     f1 = __shfl(fv, k + 1);
      const float f2 = __shfl(fv, k + 2), f3 = __shfl(fv, k + 3);
      const unsigned w0 = *(const unsigned*)(Hb + (size_t)c0 * 512);
      const unsigned w1 = *(const unsigned*)(Hb + (size_t)c1 * 512);
      const unsigned w2 = *(const unsigned*)(Hb + (size_t)c2 * 512);
      const unsigned w3 = *(const unsigned*)(Hb + (size_t)c3 * 512);
      const f32x2 l0 = __builtin_amdgcn_cvt_pk_f32_fp8(w0, false), h0 = __builtin_amdgcn_cvt_pk_f32_fp8(w0, true);
      const f32x2 l1 = __builtin_amdgcn_cvt_pk_f32_fp8(w1, false), h1 = __builtin_amdgcn_cvt_pk_f32_fp8(w1, true);
      const f32x2 l2 = __builtin_amdgcn_cvt_pk_f32_fp8(w2, false), h2 = __builtin_amdgcn_cvt_pk_f32_fp8(w2, true);
      const f32x2 l3 = __builtin_amdgcn_cvt_pk_f32_fp8(w3, false), h3 = __builtin_amdgcn_cvt_pk_f32_fp8(w3, true);
      a0.x += f0 * l0.x; a0.y += f0 * l0.y; a0.z += f0 * h0.x; a0.w += f0 * h0.y;
      a1.x += f1 * l1.x; a1.y += f1 * l1.y; a1.z += f1 * h1.x; a1.w += f1 * h1.y;
      a2.x += f2 * l2.x; a2.y += f2 * l2.y; a2.z += f2 * h2.x; a2.w += f2 * h2.y;
      a3.x += f3 * l3.x; a3.y += f3 * l3.y; a3.z += f3 * h3.x; a3.w += f3 * h3.y;
    }
    for (; k < m; ++k) {
      const int   c0 = __shfl(cv, k);
      const float f0 = __shfl(fv, k);
      const unsigned w0 = *(const unsigned*)(Hb + (size_t)c0 * 512);
      const f32x2 l0 = __builtin_amdgcn_cvt_pk_f32_fp8(w0, false), h0 = __builtin_amdgcn_cvt_pk_f32_fp8(w0, true);
      a0.x += f0 * l0.x; a0.y += f0 * l0.y; a0.z += f0 * h0.x; a0.w += f0 * h0.y;
    }
  }
  f32x4 a = (a0 + a1) + (a2 + a3);
  if (sign) sneg[r][lane] = a;
  __syncthreads();
  if (sign) {
    __builtin_nontemporal_store(a, ((f32x4*)(out + (size_t)2 * N_NODES * 256)) + (size_t)i * 64 + lane);
  } else {
    const f32x4 an = sneg[r][lane];
    const f32x4 bv = ((const f32x4*)bias)[lane];
    const f32x4 o = a - an + bv;
    __builtin_nontemporal_store(o, ((f32x4*)out) + (size_t)i * 64 + lane);
    __builtin_nontemporal_store(a, ((f32x4*)(out + (size_t)N_NODES * 256)) + (size_t)i * 64 + lane);
  }
}

extern "C" void kernel_launch(void* const* d_in, const int* in_sizes, int n_in,
                              void* d_out, int out_size, void* d_ws, size_t ws_size,
                              hipStream_t stream) {
  const float* node    = (const float*)d_in[0];
  const int*   adjp    = (const int*)d_in[1];
  const int*   adjn    = (const int*)d_in[2];
  const float* basis   = (const float*)d_in[3];
  const float* att     = (const float*)d_in[4];
  const float* mapping = (const float*)d_in[5];
  const float* bias    = (const float*)d_in[6];
  const float* theta1  = (const float*)d_in[7];
  const float* b1      = (const float*)d_in[8];
  const float* theta2  = (const float*)d_in[9];
  const float* b2      = (const float*)d_in[10];
  float* out = (float*)d_out;

  size_t off = 0;
  char* wsb = (char*)d_ws;
  auto alloc = [&](size_t bytes) -> char* {
    char* p = wsb + off;
    off = (off + bytes + 255) & ~(size_t)255;
    return p;
  };
  unsigned short* A16 = (unsigned short*)alloc((size_t)N_NODES * 256 * 2);
  unsigned char*  H8  = (unsigned char*)alloc((size_t)N_NODES * 512);
  unsigned short* Wt  = (unsigned short*)alloc(512 * 256 * 2);
  float* biasvec = (float*)alloc(512 * 4);
  float* sdbuf = (float*)alloc((size_t)16 * N_NODES * 4);  // 16 partial-dot slices
  f32x4* nip = (f32x4*)alloc((size_t)N_NODES * 16);        // {s, d, rdeg, _} pos
  f32x4* nin = (f32x4*)alloc((size_t)N_NODES * 16);        // {s, d, rdeg, _} neg
  int* cnt2 = (int*)alloc((size_t)2 * N_NODES * 4);        // cntp | cntn (one memset)
  int* cntp = cnt2, *cntn = cnt2 + N_NODES;
  int* cur2 = (int*)alloc((size_t)2 * N_NODES * 4);        // initialized by scan3
  int* curp = cur2, *curn = cur2 + N_NODES;
  int* rsp = (int*)alloc((N_NODES + 1) * 4);
  int* rsn = (int*)alloc((N_NODES + 1) * 4);
  int* bsp = (int*)alloc(NSB * 4);
  int* bsn = (int*)alloc(NSB * 4);
  i32x2* ecp = (i32x2*)alloc((size_t)NEDGE * 8);           // packed {dst, coeff}
  i32x2* ecn = (i32x2*)alloc((size_t)NEDGE * 8);

  (void)hipMemsetAsync(cnt2, 0, (size_t)2 * N_NODES * 4, stream);

  fused0_kernel<<<512 + 2048 + (2 * NEDGE) / 256, 256, 0, stream>>>(
      basis, att, theta1, theta2, b1, b2, Wt, biasvec, node, A16, adjp, adjn, cntp, cntn);
  gemm_kernel<<<dim3(4, 391), 256, 0, stream>>>(A16, Wt, biasvec, mapping, H8, sdbuf);
  scan1_kernel<<<NSB, SB, 0, stream>>>(cntp, cntn, bsp, bsn);
  scan2_kernel<<<1, 128, 0, stream>>>(bsp, bsn, rsp, rsn);
  scan3_kernel<<<NSB, SB, 0, stream>>>(cntp, cntn, bsp, bsn, sdbuf, rsp, rsn, curp, curn, nip, nin);
  scatter_kernel<<<(2 * NEDGE) / 256, 256, 0, stream>>>(adjp, adjn, nip, nin, curp, curn, ecp, ecn);
  agg_kernel<<<N_NODES / 2, 256, 0, stream>>>(H8, rsp, ecp, rsn, ecn, bias, out);
}